// Round 7
// baseline (370.950 us; speedup 1.0000x reference)
//
#include <hip/hip_runtime.h>
#include <stdint.h>

// ---------------------------------------------------------------------------
// NRI-style graph block, v7: BARRIER-FREE edge MLP.
//   K0 : weights fp32->bf16 (Wo* hi/lo split for k3 accuracy)
//   K0b: hr[b,r,kap,:] = W1recv @ x_r + b1  (rank-1 receiver part, bf16, 8MB)
//   K1 : wave-independent edge MLP. Each wave owns 32 edges x 4 kap.
//        h1 in wave-PRIVATE LDS slice (same-wave write/read -> no barrier).
//        pre_msg send-feats loaded direct from inputs (gather+cvt).
//        ZERO __syncthreads. msgs written bf16.
//   K2 : receiver scatter-sum (bf16 msgs -> f32 agg)
//   K3 : node MLP split-bf16 (hi+lo 3-term MFMA) + residual
// ---------------------------------------------------------------------------

typedef __attribute__((ext_vector_type(8))) __bf16 bf16x8;
typedef __attribute__((ext_vector_type(4))) float  f32x4;

#define MFMA16(a, b, c) __builtin_amdgcn_mfma_f32_16x16x32_bf16((a), (b), (c), 0, 0, 0)

union U64q { unsigned long long u; __bf16 q[4]; };
union F32U { float f; unsigned int u; };

static __device__ __forceinline__ unsigned short bfb(__bf16 x) {
  union { __bf16 b; unsigned short u; } c; c.b = x; return c.u;
}
static __device__ __forceinline__ float bf2f(unsigned short u) {
  F32U c; c.u = ((unsigned int)u) << 16; return c.f;
}

// ---- ws layout (bytes) ----
#define WS_W1    0          // [4][256][128] bf16  (262144)
#define WS_W2    262144     // [4][64][256] bf16   (131072)
#define WS_O1H   393216     // [256][128] bf16 hi  (65536)
#define WS_O1L   458752
#define WS_O2H   524288     // [256][256] bf16     (131072)
#define WS_O2L   655360
#define WS_O3H   786432     // [64][256] bf16      (32768)
#define WS_O3L   819200
#define WS_AGG   1048576    // [B*N][64] f32       (1048576)
#define WS_HR    2097152    // [64][64][4][256] bf16 (8388608)
#define WS_MSGS  10485760   // [64][4032][64] bf16 (33030144)
#define WS_NEED  43515904   // 41.5 MB  (known-safe: R1 used 65 MB)

// ===========================================================================
// K0: weight conversion
// ===========================================================================
__global__ __launch_bounds__(256) void k0_convert(
    const float* __restrict__ W1, const float* __restrict__ W2,
    const float* __restrict__ Wo1, const float* __restrict__ Wo2,
    const float* __restrict__ Wo3, char* __restrict__ ws) {
  int i = blockIdx.x * 256 + threadIdx.x;
  __bf16* w1  = (__bf16*)(ws + WS_W1);
  __bf16* w2  = (__bf16*)(ws + WS_W2);
  __bf16* o1h = (__bf16*)(ws + WS_O1H);
  __bf16* o1l = (__bf16*)(ws + WS_O1L);
  __bf16* o2h = (__bf16*)(ws + WS_O2H);
  __bf16* o2l = (__bf16*)(ws + WS_O2L);
  __bf16* o3h = (__bf16*)(ws + WS_O3H);
  __bf16* o3l = (__bf16*)(ws + WS_O3L);
  if (i < 131072) { w1[i] = (__bf16)W1[i]; return; }
  i -= 131072;
  if (i < 65536) { w2[i] = (__bf16)W2[i]; return; }
  i -= 65536;
  if (i < 32768) { float v = Wo1[i]; __bf16 h = (__bf16)v; o1h[i] = h; o1l[i] = (__bf16)(v - (float)h); return; }
  i -= 32768;
  if (i < 65536) { float v = Wo2[i]; __bf16 h = (__bf16)v; o2h[i] = h; o2l[i] = (__bf16)(v - (float)h); return; }
  i -= 65536;
  if (i < 16384) { float v = Wo3[i]; __bf16 h = (__bf16)v; o3h[i] = h; o3l[i] = (__bf16)(v - (float)h); return; }
}

// ===========================================================================
// K0b: hr[b][r][kap][col] = W1recv[kap][col][:]@inputs[b,r,:] + b1[kap][col]
// grid 64 (one per batch), 256 thr; wave w = kap. MFMA, bf16 out.
// ===========================================================================
__global__ __launch_bounds__(256) void k0b_hr(
    const float* __restrict__ inputs, const float* __restrict__ b1g,
    const char* __restrict__ wsr, char* __restrict__ hrout) {
  const int b = blockIdx.x;
  const int tid = threadIdx.x, l = tid & 63, w = tid >> 6;  // w = kap
  const int lg = l >> 4, lr = l & 15;

  // B-frags: inputs[b][r][k]; n=r=nt*16+lr, k=kc*32+lg*8+{0..7}
  bf16x8 bfr[4][2];
#pragma unroll
  for (int nt = 0; nt < 4; ++nt)
#pragma unroll
    for (int kc = 0; kc < 2; ++kc) {
      const float* p = inputs + ((size_t)b * 64 + nt * 16 + lr) * 64 + kc * 32 + lg * 8;
      f32x4 v0 = *(const f32x4*)p, v1 = *(const f32x4*)(p + 4);
      bf16x8 t;
#pragma unroll
      for (int j = 0; j < 4; ++j) { t[j] = (__bf16)v0[j]; t[4 + j] = (__bf16)v1[j]; }
      bfr[nt][kc] = t;
    }

  const char* w1 = wsr + WS_W1;
#pragma unroll
  for (int cb = 0; cb < 4; ++cb) {          // col chunk of 64 within this kap
    f32x4 acc[4][4] = {};
#pragma unroll
    for (int kc = 0; kc < 2; ++kc)
#pragma unroll
      for (int mt = 0; mt < 4; ++mt) {
        int col = w * 256 + cb * 64 + mt * 16 + lr;
        bf16x8 af = *(const bf16x8*)(w1 + (col << 8) + kc * 64 + (lg << 4));  // recv half
#pragma unroll
        for (int nt = 0; nt < 4; ++nt)
          acc[mt][nt] = MFMA16(af, bfr[nt][kc], acc[mt][nt]);
      }
#pragma unroll
    for (int mt = 0; mt < 4; ++mt) {
      int col0 = cb * 64 + mt * 16 + (lg << 2);
      f32x4 bv = *(const f32x4*)(b1g + w * 256 + col0);
#pragma unroll
      for (int nt = 0; nt < 4; ++nt) {
        int r = nt * 16 + lr;
        U64q pk;
#pragma unroll
        for (int i2 = 0; i2 < 4; ++i2) pk.q[i2] = (__bf16)(acc[mt][nt][i2] + bv[i2]);
        *(unsigned long long*)(hrout + ((((size_t)b * 64 + r) * 4 + w) * 256 + col0) * 2) = pk.u;
      }
    }
  }
}

// ===========================================================================
// K1 v7: barrier-free. 2016 blocks x 256 thr; wave = 32 edges x 4 kap.
// h1 in wave-private LDS [32][512B] swz. G1 K=64 (send only; recv via hr).
// ===========================================================================
__global__ __launch_bounds__(256) void k1_edge(
    const float* __restrict__ inputs, const float* __restrict__ rel_type,
    const float* __restrict__ b2g, const char* __restrict__ wsr,
    __bf16* __restrict__ msgs) {
  __shared__ char sm[65536];
  const int tid = threadIdx.x, l = tid & 63, w = tid >> 6;
  const int lg = l >> 4, lr = l & 15;
  char* h1s = sm + w * 16384;            // wave-private [32 slots][512B]

  const int g = blockIdx.x * 4 + w;      // unit id 0..8063
  const int b = g / 126;
  const int u = g - b * 126;
  const int e0 = u * 32;

  // per-lane slot indices (nt=0,1): receiver r, sender s
  int rr[2], ss[2];
#pragma unroll
  for (int nt = 0; nt < 2; ++nt) {
    int e = e0 + nt * 16 + lr;
    int r = e / 63;
    int j = e - r * 63;
    rr[nt] = r;
    ss[nt] = j + (j >= r ? 1 : 0);
  }

  // rel_type gates
  float rt[2][4];
#pragma unroll
  for (int nt = 0; nt < 2; ++nt) {
    f32x4 rv = *(const f32x4*)(rel_type + ((size_t)b * 4032 + e0 + nt * 16 + lr) * 4);
#pragma unroll
    for (int kap = 0; kap < 4; ++kap) rt[nt][kap] = rv[kap];
  }

  // B-frags: send feats, pre[slot][k] = inputs[b][s][k], k=kc*32+lg*8+{0..7}
  bf16x8 bs[2][2];
#pragma unroll
  for (int nt = 0; nt < 2; ++nt)
#pragma unroll
    for (int kc = 0; kc < 2; ++kc) {
      const float* p = inputs + ((size_t)b * 64 + ss[nt]) * 64 + kc * 32 + lg * 8;
      f32x4 v0 = *(const f32x4*)p, v1 = *(const f32x4*)(p + 4);
      bf16x8 t;
#pragma unroll
      for (int j = 0; j < 4; ++j) { t[j] = (__bf16)v0[j]; t[4 + j] = (__bf16)v1[j]; }
      bs[nt][kc] = t;
    }

  const char* w1  = wsr + WS_W1;
  const char* w2  = wsr + WS_W2;
  const char* hrp = wsr + WS_HR;

  f32x4 macc[4][2] = {};

  for (int kap = 0; kap < 4; ++kap) {
    // ===== G1: h1send^T = W1send @ send^T (M=256, N=32, K=64), M in halves =====
#pragma unroll
    for (int half = 0; half < 2; ++half) {
      f32x4 acc1[8][2] = {};
#pragma unroll
      for (int kc = 0; kc < 2; ++kc)
#pragma unroll
        for (int mt = 0; mt < 8; ++mt) {
          int colp = half * 128 + mt * 16 + lr;
          bf16x8 af = *(const bf16x8*)(w1 + (((size_t)kap * 256 + colp) << 8) + 128 + kc * 64 + (lg << 4));
          acc1[mt][0] = MFMA16(af, bs[0][kc], acc1[mt][0]);
          acc1[mt][1] = MFMA16(af, bs[1][kc], acc1[mt][1]);
        }
      // epilogue: + hr (recv part incl. b1), relu, bf16 -> wave-private LDS
#pragma unroll
      for (int mt = 0; mt < 8; ++mt) {
        int col0 = half * 128 + mt * 16 + (lg << 2);
#pragma unroll
        for (int nt = 0; nt < 2; ++nt) {
          U64q hv;
          hv.u = *(const unsigned long long*)(hrp + ((((size_t)b * 64 + rr[nt]) * 4 + kap) * 256 + col0) * 2);
          int slot = nt * 16 + lr;
          U64q pk;
#pragma unroll
          for (int i2 = 0; i2 < 4; ++i2) {
            float x = acc1[mt][nt][i2] + (float)hv.q[i2];
            pk.q[i2] = (__bf16)fmaxf(x, 0.f);
          }
          int off = (slot * 512 + col0 * 2) ^ ((lr & 7) << 4);
          *(unsigned long long*)(h1s + off) = pk.u;
        }
      }
    }
    // ===== G2: h2^T = W2 @ h1^T (M=64, N=32, K=256) — same wave, no barrier =====
    f32x4 acc2[4][2] = {};
#pragma unroll
    for (int kc2 = 0; kc2 < 8; ++kc2) {
      bf16x8 b2f[2];
#pragma unroll
      for (int nt = 0; nt < 2; ++nt) {
        int off = ((nt * 16 + lr) * 512 + kc2 * 64 + (lg << 4)) ^ ((lr & 7) << 4);
        b2f[nt] = *(const bf16x8*)(h1s + off);
      }
#pragma unroll
      for (int mt2 = 0; mt2 < 4; ++mt2) {
        bf16x8 a2 = *(const bf16x8*)(w2 + (((size_t)kap * 64 + mt2 * 16 + lr) << 9) + kc2 * 64 + (lg << 4));
#pragma unroll
        for (int nt = 0; nt < 2; ++nt)
          acc2[mt2][nt] = MFMA16(a2, b2f[nt], acc2[mt2][nt]);
      }
    }
    // gate: macc += relu(acc2 + b2) * rel_type[kap]
#pragma unroll
    for (int mt2 = 0; mt2 < 4; ++mt2) {
      int col0 = mt2 * 16 + (lg << 2);
      f32x4 bv = *(const f32x4*)(b2g + kap * 64 + col0);
#pragma unroll
      for (int nt = 0; nt < 2; ++nt) {
        float gv = rt[nt][kap];
#pragma unroll
        for (int i2 = 0; i2 < 4; ++i2)
          macc[mt2][nt][i2] += fmaxf(acc2[mt2][nt][i2] + bv[i2], 0.f) * gv;
      }
    }
  }

  // ---- write msgs (bf16, 4 consecutive feats per lane) ----
#pragma unroll
  for (int mt2 = 0; mt2 < 4; ++mt2) {
    int col0 = mt2 * 16 + (lg << 2);
#pragma unroll
    for (int nt = 0; nt < 2; ++nt) {
      int e = e0 + nt * 16 + lr;
      U64q pk;
#pragma unroll
      for (int i2 = 0; i2 < 4; ++i2) pk.q[i2] = (__bf16)macc[mt2][nt][i2];
      *(unsigned long long*)((char*)msgs + (((size_t)b * 4032 + e) * 64 + col0) * 2) = pk.u;
    }
  }
}

// ===========================================================================
// K2: receiver scatter-sum. agg[b,n,:] = sum_j msgs[b, n*63+j, :]  (bf16 in)
// ===========================================================================
__global__ __launch_bounds__(256) void k2_agg(const unsigned short* __restrict__ msgs,
                                              float* __restrict__ agg) {
  int tid = threadIdx.x;
  int m  = tid & 63;
  int rl = tid >> 6;
  int row = blockIdx.x * 4 + rl;     // 0..4095
  int b = row >> 6, n = row & 63;
  const unsigned short* src = msgs + ((size_t)(b * 4032 + n * 63)) * 64 + m;
  float s0 = 0.f, s1 = 0.f, s2 = 0.f;
#pragma unroll 7
  for (int j = 0; j < 63; j += 3) {
    s0 += bf2f(src[j * 64]);
    s1 += bf2f(src[(j + 1) * 64]);
    s2 += bf2f(src[(j + 2) * 64]);
  }
  agg[row * 64 + m] = s0 + s1 + s2;
}

// ===========================================================================
// K3: node MLP with split-bf16 (hi+lo) 3-term MFMA + residual (unchanged)
// ===========================================================================
__global__ __launch_bounds__(256) void k3_node(
    const float* __restrict__ inputs, const float* __restrict__ agg,
    const char* __restrict__ wsr,
    const float* __restrict__ bo1, const float* __restrict__ bo2,
    const float* __restrict__ bo3, float* __restrict__ out) {
  __shared__ char sm[65536];
  char* augHi = sm;                  // [32][128] bf16 swz
  char* augLo = sm + 8192;
  char* h1hi  = sm + 16384;          // [32][256] bf16 swz
  char* h1lo  = sm + 32768;
  char* h2hi  = sm;                  // reuse aug region after GEMM1
  char* h2lo  = sm + 49152;

  const char* o1h = wsr + WS_O1H;
  const char* o1l = wsr + WS_O1L;
  const char* o2h = wsr + WS_O2H;
  const char* o2l = wsr + WS_O2L;
  const char* o3h = wsr + WS_O3H;
  const char* o3l = wsr + WS_O3L;

  const int tid = threadIdx.x;
  const int l = tid & 63;
  const int w = tid >> 6;
  const int lg = l >> 4, lr = l & 15;
  const int r0 = blockIdx.x * 32;

  for (int it = 0; it < 8; ++it) {
    int u = tid + it * 256;
    int row = u >> 6, up = u & 63;
    int col = up * 2;
    const float* src = (col < 64) ? (inputs + (r0 + row) * 64 + col)
                                  : (agg + (r0 + row) * 64 + (col - 64));
    float2 v = *(const float2*)src;
    __bf16 h0 = (__bf16)v.x, h1v = (__bf16)v.y;
    __bf16 l0 = (__bf16)(v.x - (float)h0), l1 = (__bf16)(v.y - (float)h1v);
    int off = (row * 256 + col * 2) ^ ((row & 7) << 4);
    ushort2 ph; ph.x = bfb(h0); ph.y = bfb(h1v);
    ushort2 pl; pl.x = bfb(l0); pl.y = bfb(l1);
    *(ushort2*)(augHi + off) = ph;
    *(ushort2*)(augLo + off) = pl;
  }
  __syncthreads();

  f32x4 acc[4][2] = {};
#pragma unroll
  for (int kk = 0; kk < 4; ++kk) {
    bf16x8 ah[4], al[4], bh[2], bl[2];
#pragma unroll
    for (int mfi = 0; mfi < 4; ++mfi) {
      int colp = w * 64 + mfi * 16 + lr;
      int gb = colp * 256 + kk * 64 + (lg << 4);
      ah[mfi] = *(const bf16x8*)(o1h + gb);
      al[mfi] = *(const bf16x8*)(o1l + gb);
    }
#pragma unroll
    for (int nfi = 0; nfi < 2; ++nfi) {
      int row = nfi * 16 + lr;
      int off = (row * 256 + kk * 64 + (lg << 4)) ^ ((row & 7) << 4);
      bh[nfi] = *(const bf16x8*)(augHi + off);
      bl[nfi] = *(const bf16x8*)(augLo + off);
    }
#pragma unroll
    for (int mfi = 0; mfi < 4; ++mfi)
#pragma unroll
      for (int nfi = 0; nfi < 2; ++nfi) {
        acc[mfi][nfi] = MFMA16(ah[mfi], bh[nfi], acc[mfi][nfi]);
        acc[mfi][nfi] = MFMA16(ah[mfi], bl[nfi], acc[mfi][nfi]);
        acc[mfi][nfi] = MFMA16(al[mfi], bh[nfi], acc[mfi][nfi]);
      }
  }
#pragma unroll
  for (int mfi = 0; mfi < 4; ++mfi) {
    int col0 = w * 64 + mfi * 16 + (lg << 2);
    f32x4 bv = *(const f32x4*)(bo1 + col0);
#pragma unroll
    for (int nfi = 0; nfi < 2; ++nfi) {
      int row = nfi * 16 + lr;
      U64q ph, pl;
#pragma unroll
      for (int i2 = 0; i2 < 4; ++i2) {
        float x = fmaxf(acc[mfi][nfi][i2] + bv[i2], 0.f);
        ph.q[i2] = (__bf16)x;
        pl.q[i2] = (__bf16)(x - (float)ph.q[i2]);
      }
      int off = (row * 512 + col0 * 2) ^ ((row & 7) << 4);
      *(unsigned long long*)(h1hi + off) = ph.u;
      *(unsigned long long*)(h1lo + off) = pl.u;
    }
  }
  __syncthreads();

  f32x4 acc2[4][2] = {};
#pragma unroll
  for (int kk = 0; kk < 8; ++kk) {
    bf16x8 ah[4], al[4], bh[2], bl[2];
#pragma unroll
    for (int mfi = 0; mfi < 4; ++mfi) {
      int colp = w * 64 + mfi * 16 + lr;
      int gb = colp * 512 + kk * 64 + (lg << 4);
      ah[mfi] = *(const bf16x8*)(o2h + gb);
      al[mfi] = *(const bf16x8*)(o2l + gb);
    }
#pragma unroll
    for (int nfi = 0; nfi < 2; ++nfi) {
      int row = nfi * 16 + lr;
      int off = (row * 512 + kk * 64 + (lg << 4)) ^ ((row & 7) << 4);
      bh[nfi] = *(const bf16x8*)(h1hi + off);
      bl[nfi] = *(const bf16x8*)(h1lo + off);
    }
#pragma unroll
    for (int mfi = 0; mfi < 4; ++mfi)
#pragma unroll
      for (int nfi = 0; nfi < 2; ++nfi) {
        acc2[mfi][nfi] = MFMA16(ah[mfi], bh[nfi], acc2[mfi][nfi]);
        acc2[mfi][nfi] = MFMA16(ah[mfi], bl[nfi], acc2[mfi][nfi]);
        acc2[mfi][nfi] = MFMA16(al[mfi], bh[nfi], acc2[mfi][nfi]);
      }
  }
#pragma unroll
  for (int mfi = 0; mfi < 4; ++mfi) {
    int col0 = w * 64 + mfi * 16 + (lg << 2);
    f32x4 bv = *(const f32x4*)(bo2 + col0);
#pragma unroll
    for (int nfi = 0; nfi < 2; ++nfi) {
      int row = nfi * 16 + lr;
      U64q ph, pl;
#pragma unroll
      for (int i2 = 0; i2 < 4; ++i2) {
        float x = fmaxf(acc2[mfi][nfi][i2] + bv[i2], 0.f);
        ph.q[i2] = (__bf16)x;
        pl.q[i2] = (__bf16)(x - (float)ph.q[i2]);
      }
      int off = (row * 512 + col0 * 2) ^ ((row & 7) << 4);
      *(unsigned long long*)(h2hi + off) = ph.u;
      *(unsigned long long*)(h2lo + off) = pl.u;
    }
  }
  __syncthreads();

  f32x4 acc3[2] = {};
#pragma unroll
  for (int kk = 0; kk < 8; ++kk) {
    int colp = w * 16 + lr;
    int gb = colp * 512 + kk * 64 + (lg << 4);
    bf16x8 a3h = *(const bf16x8*)(o3h + gb);
    bf16x8 a3l = *(const bf16x8*)(o3l + gb);
#pragma unroll
    for (int nfi = 0; nfi < 2; ++nfi) {
      int row = nfi * 16 + lr;
      int off = (row * 512 + kk * 64 + (lg << 4)) ^ ((row & 7) << 4);
      bf16x8 b3h = *(const bf16x8*)(h2hi + off);
      bf16x8 b3l = *(const bf16x8*)(h2lo + off);
      acc3[nfi] = MFMA16(a3h, b3h, acc3[nfi]);
      acc3[nfi] = MFMA16(a3h, b3l, acc3[nfi]);
      acc3[nfi] = MFMA16(a3l, b3h, acc3[nfi]);
    }
  }
#pragma unroll
  for (int nfi = 0; nfi < 2; ++nfi) {
    int row = nfi * 16 + lr;
    int col0 = w * 16 + (lg << 2);
    f32x4 bv = *(const f32x4*)(bo3 + col0);
    f32x4 iv = *(const f32x4*)(inputs + (r0 + row) * 64 + col0);
    f32x4 o;
#pragma unroll
    for (int i2 = 0; i2 < 4; ++i2) o[i2] = acc3[nfi][i2] + bv[i2] + iv[i2];
    *(f32x4*)(out + (r0 + row) * 64 + col0) = o;
  }
}

// ===========================================================================
extern "C" void kernel_launch(void* const* d_in, const int* in_sizes, int n_in,
                              void* d_out, int out_size, void* d_ws, size_t ws_size,
                              hipStream_t stream) {
  (void)in_sizes; (void)n_in; (void)out_size;
  if (ws_size < (size_t)WS_NEED) return;  // 41.5 MB (R1 proved >= 65 MB avail)

  const float* inputs   = (const float*)d_in[0];
  const float* rel_type = (const float*)d_in[1];
  const float* W1  = (const float*)d_in[4];
  const float* b1  = (const float*)d_in[5];
  const float* W2  = (const float*)d_in[6];
  const float* b2  = (const float*)d_in[7];
  const float* Wo1 = (const float*)d_in[8];
  const float* bo1 = (const float*)d_in[9];
  const float* Wo2 = (const float*)d_in[10];
  const float* bo2 = (const float*)d_in[11];
  const float* Wo3 = (const float*)d_in[12];
  const float* bo3 = (const float*)d_in[13];

  char* ws = (char*)d_ws;
  float*  agg  = (float*)(ws + WS_AGG);
  __bf16* msgs = (__bf16*)(ws + WS_MSGS);
  float*  out  = (float*)d_out;

  k0_convert<<<dim3(1216), dim3(256), 0, stream>>>(W1, W2, Wo1, Wo2, Wo3, ws);
  k0b_hr<<<dim3(64), dim3(256), 0, stream>>>(inputs, b1, ws, ws + WS_HR);
  k1_edge<<<dim3(2016), dim3(256), 0, stream>>>(inputs, rel_type, b2, ws, msgs);
  k2_agg<<<dim3(1024), dim3(256), 0, stream>>>((const unsigned short*)msgs, agg);
  k3_node<<<dim3(128), dim3(256), 0, stream>>>(inputs, agg, ws, bo1, bo2, bo3, out);
}

// Round 8
// 327.096 us; speedup vs baseline: 1.1341x; 1.1341x over previous
//
#include <hip/hip_runtime.h>
#include <stdint.h>

// ---------------------------------------------------------------------------
// NRI-style graph block, v8: SMALL-CODE barrier-free edge MLP.
// R1-R7 invariance (250-350us regardless of barriers/LDS/occupancy, all pipes
// <20%) points to I$ thrash: fully-unrolled bodies were 30-50KB. v8 rolls the
// outer loops (#pragma unroll 1) so k1's body is ~2KB; accumulator arrays are
// only indexed by unrolled inner loops (reg-alloc safe, rule #20).
//   K0 : weights fp32->bf16 (Wo* hi/lo split for k3 accuracy)
//   K0b: hr[b,r,kap,:] = W1recv @ x_r + b1  (rank-1 receiver part, bf16)
//   K1 : wave = 32 edges x 4 kap, wave-private 8KB h1 slice, G1/G2 interleaved
//        per K-half, zero __syncthreads, msgs bf16.
//   K2 : receiver scatter-sum (bf16 msgs -> f32 agg)
//   K3 : node MLP split-bf16 (hi+lo 3-term MFMA) + residual
// ---------------------------------------------------------------------------

typedef __attribute__((ext_vector_type(8))) __bf16 bf16x8;
typedef __attribute__((ext_vector_type(4))) float  f32x4;

#define MFMA16(a, b, c) __builtin_amdgcn_mfma_f32_16x16x32_bf16((a), (b), (c), 0, 0, 0)

union U64q { unsigned long long u; __bf16 q[4]; };
union F32U { float f; unsigned int u; };

static __device__ __forceinline__ unsigned short bfb(__bf16 x) {
  union { __bf16 b; unsigned short u; } c; c.b = x; return c.u;
}
static __device__ __forceinline__ float bf2f(unsigned short u) {
  F32U c; c.u = ((unsigned int)u) << 16; return c.f;
}

// ---- ws layout (bytes) ----
#define WS_W1    0          // [4][256][128] bf16  (262144)
#define WS_W2    262144     // [4][64][256] bf16   (131072)
#define WS_O1H   393216     // [256][128] bf16 hi  (65536)
#define WS_O1L   458752
#define WS_O2H   524288     // [256][256] bf16     (131072)
#define WS_O2L   655360
#define WS_O3H   786432     // [64][256] bf16      (32768)
#define WS_O3L   819200
#define WS_AGG   1048576    // [B*N][64] f32       (1048576)
#define WS_HR    2097152    // [64][64][4][256] bf16 (8388608)
#define WS_MSGS  10485760   // [64][4032][64] bf16 (33030144)
#define WS_NEED  43515904

// ===========================================================================
// K0: weight conversion
// ===========================================================================
__global__ __launch_bounds__(256) void k0_convert(
    const float* __restrict__ W1, const float* __restrict__ W2,
    const float* __restrict__ Wo1, const float* __restrict__ Wo2,
    const float* __restrict__ Wo3, char* __restrict__ ws) {
  int i = blockIdx.x * 256 + threadIdx.x;
  __bf16* w1  = (__bf16*)(ws + WS_W1);
  __bf16* w2  = (__bf16*)(ws + WS_W2);
  __bf16* o1h = (__bf16*)(ws + WS_O1H);
  __bf16* o1l = (__bf16*)(ws + WS_O1L);
  __bf16* o2h = (__bf16*)(ws + WS_O2H);
  __bf16* o2l = (__bf16*)(ws + WS_O2L);
  __bf16* o3h = (__bf16*)(ws + WS_O3H);
  __bf16* o3l = (__bf16*)(ws + WS_O3L);
  if (i < 131072) { w1[i] = (__bf16)W1[i]; return; }
  i -= 131072;
  if (i < 65536) { w2[i] = (__bf16)W2[i]; return; }
  i -= 65536;
  if (i < 32768) { float v = Wo1[i]; __bf16 h = (__bf16)v; o1h[i] = h; o1l[i] = (__bf16)(v - (float)h); return; }
  i -= 32768;
  if (i < 65536) { float v = Wo2[i]; __bf16 h = (__bf16)v; o2h[i] = h; o2l[i] = (__bf16)(v - (float)h); return; }
  i -= 65536;
  if (i < 16384) { float v = Wo3[i]; __bf16 h = (__bf16)v; o3h[i] = h; o3l[i] = (__bf16)(v - (float)h); return; }
}

// ===========================================================================
// K0b: hr[b][r][kap][col] = W1recv[kap][col][:]@inputs[b,r,:] + b1[kap][col]
// grid 64, 256 thr; wave w = kap. Rolled over col chunks.
// ===========================================================================
__global__ __launch_bounds__(256) void k0b_hr(
    const float* __restrict__ inputs, const float* __restrict__ b1g,
    const char* __restrict__ wsr, char* __restrict__ hrout) {
  const int b = blockIdx.x;
  const int tid = threadIdx.x, l = tid & 63, w = tid >> 6;  // w = kap
  const int lg = l >> 4, lr = l & 15;

  bf16x8 bfr[4][2];
#pragma unroll
  for (int nt = 0; nt < 4; ++nt)
#pragma unroll
    for (int kc = 0; kc < 2; ++kc) {
      const float* p = inputs + ((size_t)b * 64 + nt * 16 + lr) * 64 + kc * 32 + lg * 8;
      f32x4 v0 = *(const f32x4*)p, v1 = *(const f32x4*)(p + 4);
      bf16x8 t;
#pragma unroll
      for (int j = 0; j < 4; ++j) { t[j] = (__bf16)v0[j]; t[4 + j] = (__bf16)v1[j]; }
      bfr[nt][kc] = t;
    }

  const char* w1 = wsr + WS_W1;
#pragma unroll 1
  for (int cb = 0; cb < 4; ++cb) {          // col chunk of 64 within this kap
    f32x4 acc[4][4] = {};
#pragma unroll
    for (int kc = 0; kc < 2; ++kc)
#pragma unroll
      for (int mt = 0; mt < 4; ++mt) {
        int col = w * 256 + cb * 64 + mt * 16 + lr;
        bf16x8 af = *(const bf16x8*)(w1 + (col << 8) + kc * 64 + (lg << 4));
#pragma unroll
        for (int nt = 0; nt < 4; ++nt)
          acc[mt][nt] = MFMA16(af, bfr[nt][kc], acc[mt][nt]);
      }
#pragma unroll
    for (int mt = 0; mt < 4; ++mt) {
      int col0 = cb * 64 + mt * 16 + (lg << 2);
      f32x4 bv = *(const f32x4*)(b1g + w * 256 + col0);
#pragma unroll
      for (int nt = 0; nt < 4; ++nt) {
        int r = nt * 16 + lr;
        U64q pk;
#pragma unroll
        for (int i2 = 0; i2 < 4; ++i2) pk.q[i2] = (__bf16)(acc[mt][nt][i2] + bv[i2]);
        *(unsigned long long*)(hrout + ((((size_t)b * 64 + r) * 4 + w) * 256 + col0) * 2) = pk.u;
      }
    }
  }
}

// ===========================================================================
// K1 v8: barrier-free, small code. 2016 blocks x 256 thr; wave = 32 edges.
// Rolled: kap(4) x half(2) x { cb(2): G1 64-col chunk -> h1 8KB slice; then
// kc2(4): G2 K-half partial }. Unrolled only mt/nt/kc (accumulator indices).
// ===========================================================================
__global__ __launch_bounds__(256) void k1_edge(
    const float* __restrict__ inputs, const float* __restrict__ rel_type,
    const float* __restrict__ b2g, const char* __restrict__ wsr,
    __bf16* __restrict__ msgs) {
  __shared__ char sm[32768];
  const int tid = threadIdx.x, l = tid & 63, w = tid >> 6;
  const int lg = l >> 4, lr = l & 15;
  char* h1s = sm + w * 8192;             // wave-private [32 slots][256B] (one K-half)

  const int g = blockIdx.x * 4 + w;      // unit id 0..8063
  const int b = g / 126;
  const int u = g - b * 126;
  const int e0 = u * 32;

  int rr[2], ss[2];
#pragma unroll
  for (int nt = 0; nt < 2; ++nt) {
    int e = e0 + nt * 16 + lr;
    int r = e / 63;
    int j = e - r * 63;
    rr[nt] = r;
    ss[nt] = j + (j >= r ? 1 : 0);
  }

  // B-frags: send feats (loaded once, 16 VGPR)
  bf16x8 bs[2][2];
#pragma unroll
  for (int nt = 0; nt < 2; ++nt)
#pragma unroll
    for (int kc = 0; kc < 2; ++kc) {
      const float* p = inputs + ((size_t)b * 64 + ss[nt]) * 64 + kc * 32 + lg * 8;
      f32x4 v0 = *(const f32x4*)p, v1 = *(const f32x4*)(p + 4);
      bf16x8 t;
#pragma unroll
      for (int j = 0; j < 4; ++j) { t[j] = (__bf16)v0[j]; t[4 + j] = (__bf16)v1[j]; }
      bs[nt][kc] = t;
    }

  const char* w1  = wsr + WS_W1;
  const char* w2  = wsr + WS_W2;
  const char* hrp = wsr + WS_HR;

  f32x4 macc[4][2] = {};

#pragma unroll 1
  for (int kap = 0; kap < 4; ++kap) {
    f32x4 acc2[4][2] = {};
    // rel_type gates for this kap (scalar loads, L2-hot)
    float rt0 = rel_type[((size_t)b * 4032 + e0 + lr) * 4 + kap];
    float rt1 = rel_type[((size_t)b * 4032 + e0 + 16 + lr) * 4 + kap];

#pragma unroll 1
    for (int half = 0; half < 2; ++half) {
      // ===== G1: two 64-col chunks -> h1s (128 cols of this half) =====
#pragma unroll 1
      for (int cb = 0; cb < 2; ++cb) {
        f32x4 acc1[4][2] = {};
#pragma unroll
        for (int kc = 0; kc < 2; ++kc)
#pragma unroll
          for (int mt = 0; mt < 4; ++mt) {
            int colp = half * 128 + cb * 64 + mt * 16 + lr;
            bf16x8 af = *(const bf16x8*)(w1 + (((size_t)kap * 256 + colp) << 8) + 128 + kc * 64 + (lg << 4));
            acc1[mt][0] = MFMA16(af, bs[0][kc], acc1[mt][0]);
            acc1[mt][1] = MFMA16(af, bs[1][kc], acc1[mt][1]);
          }
        // epilogue: + hr (recv part incl b1), relu, bf16 -> wave-private LDS
#pragma unroll
        for (int mt = 0; mt < 4; ++mt) {
          int col0 = half * 128 + cb * 64 + mt * 16 + (lg << 2);
          int lc   = cb * 64 + mt * 16 + (lg << 2);     // col within half
#pragma unroll
          for (int nt = 0; nt < 2; ++nt) {
            U64q hv;
            hv.u = *(const unsigned long long*)(hrp + ((((size_t)b * 64 + rr[nt]) * 4 + kap) * 256 + col0) * 2);
            int slot = nt * 16 + lr;
            U64q pk;
#pragma unroll
            for (int i2 = 0; i2 < 4; ++i2)
              pk.q[i2] = (__bf16)fmaxf(acc1[mt][nt][i2] + (float)hv.q[i2], 0.f);
            int off = (slot * 256 + lc * 2) ^ ((slot & 7) << 4);
            *(unsigned long long*)(h1s + off) = pk.u;
          }
        }
      }
      // ===== G2 partial: K window [half*128, +128) — same wave, no barrier =====
#pragma unroll 1
      for (int kc2 = 0; kc2 < 4; ++kc2) {
        bf16x8 b2f[2];
#pragma unroll
        for (int nt = 0; nt < 2; ++nt) {
          int slot = nt * 16 + lr;
          int off = (slot * 256 + (kc2 * 32 + lg * 8) * 2) ^ ((slot & 7) << 4);
          b2f[nt] = *(const bf16x8*)(h1s + off);
        }
#pragma unroll
        for (int mt2 = 0; mt2 < 4; ++mt2) {
          bf16x8 a2 = *(const bf16x8*)(w2 + (((size_t)kap * 64 + mt2 * 16 + lr) << 9)
                                       + half * 256 + kc2 * 64 + (lg << 4));
          acc2[mt2][0] = MFMA16(a2, b2f[0], acc2[mt2][0]);
          acc2[mt2][1] = MFMA16(a2, b2f[1], acc2[mt2][1]);
        }
      }
    }
    // gate: macc += relu(acc2 + b2) * rel_type[kap]
#pragma unroll
    for (int mt2 = 0; mt2 < 4; ++mt2) {
      f32x4 bv = *(const f32x4*)(b2g + kap * 64 + mt2 * 16 + (lg << 2));
#pragma unroll
      for (int i2 = 0; i2 < 4; ++i2) {
        macc[mt2][0][i2] += fmaxf(acc2[mt2][0][i2] + bv[i2], 0.f) * rt0;
        macc[mt2][1][i2] += fmaxf(acc2[mt2][1][i2] + bv[i2], 0.f) * rt1;
      }
    }
  }

  // ---- write msgs (bf16, 4 consecutive feats per lane) ----
#pragma unroll
  for (int mt2 = 0; mt2 < 4; ++mt2) {
    int col0 = mt2 * 16 + (lg << 2);
#pragma unroll
    for (int nt = 0; nt < 2; ++nt) {
      int e = e0 + nt * 16 + lr;
      U64q pk;
#pragma unroll
      for (int i2 = 0; i2 < 4; ++i2) pk.q[i2] = (__bf16)macc[mt2][nt][i2];
      *(unsigned long long*)((char*)msgs + (((size_t)b * 4032 + e) * 64 + col0) * 2) = pk.u;
    }
  }
}

// ===========================================================================
// K2: receiver scatter-sum. agg[b,n,:] = sum_j msgs[b, n*63+j, :]  (bf16 in)
// ===========================================================================
__global__ __launch_bounds__(256) void k2_agg(const unsigned short* __restrict__ msgs,
                                              float* __restrict__ agg) {
  int tid = threadIdx.x;
  int m  = tid & 63;
  int rl = tid >> 6;
  int row = blockIdx.x * 4 + rl;     // 0..4095
  int b = row >> 6, n = row & 63;
  const unsigned short* src = msgs + ((size_t)(b * 4032 + n * 63)) * 64 + m;
  float s0 = 0.f, s1 = 0.f, s2 = 0.f;
#pragma unroll 7
  for (int j = 0; j < 63; j += 3) {
    s0 += bf2f(src[j * 64]);
    s1 += bf2f(src[(j + 1) * 64]);
    s2 += bf2f(src[(j + 2) * 64]);
  }
  agg[row * 64 + m] = s0 + s1 + s2;
}

// ===========================================================================
// K3: node MLP with split-bf16 (hi+lo) 3-term MFMA + residual
// ===========================================================================
__global__ __launch_bounds__(256) void k3_node(
    const float* __restrict__ inputs, const float* __restrict__ agg,
    const char* __restrict__ wsr,
    const float* __restrict__ bo1, const float* __restrict__ bo2,
    const float* __restrict__ bo3, float* __restrict__ out) {
  __shared__ char sm[65536];
  char* augHi = sm;                  // [32][128] bf16 swz
  char* augLo = sm + 8192;
  char* h1hi  = sm + 16384;          // [32][256] bf16 swz
  char* h1lo  = sm + 32768;
  char* h2hi  = sm;                  // reuse aug region after GEMM1
  char* h2lo  = sm + 49152;

  const char* o1h = wsr + WS_O1H;
  const char* o1l = wsr + WS_O1L;
  const char* o2h = wsr + WS_O2H;
  const char* o2l = wsr + WS_O2L;
  const char* o3h = wsr + WS_O3H;
  const char* o3l = wsr + WS_O3L;

  const int tid = threadIdx.x;
  const int l = tid & 63;
  const int w = tid >> 6;
  const int lg = l >> 4, lr = l & 15;
  const int r0 = blockIdx.x * 32;

  for (int it = 0; it < 8; ++it) {
    int u = tid + it * 256;
    int row = u >> 6, up = u & 63;
    int col = up * 2;
    const float* src = (col < 64) ? (inputs + (r0 + row) * 64 + col)
                                  : (agg + (r0 + row) * 64 + (col - 64));
    float2 v = *(const float2*)src;
    __bf16 h0 = (__bf16)v.x, h1v = (__bf16)v.y;
    __bf16 l0 = (__bf16)(v.x - (float)h0), l1 = (__bf16)(v.y - (float)h1v);
    int off = (row * 256 + col * 2) ^ ((row & 7) << 4);
    ushort2 ph; ph.x = bfb(h0); ph.y = bfb(h1v);
    ushort2 pl; pl.x = bfb(l0); pl.y = bfb(l1);
    *(ushort2*)(augHi + off) = ph;
    *(ushort2*)(augLo + off) = pl;
  }
  __syncthreads();

  f32x4 acc[4][2] = {};
#pragma unroll
  for (int kk = 0; kk < 4; ++kk) {
    bf16x8 ah[4], al[4], bh[2], bl[2];
#pragma unroll
    for (int mfi = 0; mfi < 4; ++mfi) {
      int colp = w * 64 + mfi * 16 + lr;
      int gb = colp * 256 + kk * 64 + (lg << 4);
      ah[mfi] = *(const bf16x8*)(o1h + gb);
      al[mfi] = *(const bf16x8*)(o1l + gb);
    }
#pragma unroll
    for (int nfi = 0; nfi < 2; ++nfi) {
      int row = nfi * 16 + lr;
      int off = (row * 256 + kk * 64 + (lg << 4)) ^ ((row & 7) << 4);
      bh[nfi] = *(const bf16x8*)(augHi + off);
      bl[nfi] = *(const bf16x8*)(augLo + off);
    }
#pragma unroll
    for (int mfi = 0; mfi < 4; ++mfi)
#pragma unroll
      for (int nfi = 0; nfi < 2; ++nfi) {
        acc[mfi][nfi] = MFMA16(ah[mfi], bh[nfi], acc[mfi][nfi]);
        acc[mfi][nfi] = MFMA16(ah[mfi], bl[nfi], acc[mfi][nfi]);
        acc[mfi][nfi] = MFMA16(al[mfi], bh[nfi], acc[mfi][nfi]);
      }
  }
#pragma unroll
  for (int mfi = 0; mfi < 4; ++mfi) {
    int col0 = w * 64 + mfi * 16 + (lg << 2);
    f32x4 bv = *(const f32x4*)(bo1 + col0);
#pragma unroll
    for (int nfi = 0; nfi < 2; ++nfi) {
      int row = nfi * 16 + lr;
      U64q ph, pl;
#pragma unroll
      for (int i2 = 0; i2 < 4; ++i2) {
        float x = fmaxf(acc[mfi][nfi][i2] + bv[i2], 0.f);
        ph.q[i2] = (__bf16)x;
        pl.q[i2] = (__bf16)(x - (float)ph.q[i2]);
      }
      int off = (row * 512 + col0 * 2) ^ ((row & 7) << 4);
      *(unsigned long long*)(h1hi + off) = ph.u;
      *(unsigned long long*)(h1lo + off) = pl.u;
    }
  }
  __syncthreads();

  f32x4 acc2[4][2] = {};
#pragma unroll
  for (int kk = 0; kk < 8; ++kk) {
    bf16x8 ah[4], al[4], bh[2], bl[2];
#pragma unroll
    for (int mfi = 0; mfi < 4; ++mfi) {
      int colp = w * 64 + mfi * 16 + lr;
      int gb = colp * 512 + kk * 64 + (lg << 4);
      ah[mfi] = *(const bf16x8*)(o2h + gb);
      al[mfi] = *(const bf16x8*)(o2l + gb);
    }
#pragma unroll
    for (int nfi = 0; nfi < 2; ++nfi) {
      int row = nfi * 16 + lr;
      int off = (row * 512 + kk * 64 + (lg << 4)) ^ ((row & 7) << 4);
      bh[nfi] = *(const bf16x8*)(h1hi + off);
      bl[nfi] = *(const bf16x8*)(h1lo + off);
    }
#pragma unroll
    for (int mfi = 0; mfi < 4; ++mfi)
#pragma unroll
      for (int nfi = 0; nfi < 2; ++nfi) {
        acc2[mfi][nfi] = MFMA16(ah[mfi], bh[nfi], acc2[mfi][nfi]);
        acc2[mfi][nfi] = MFMA16(ah[mfi], bl[nfi], acc2[mfi][nfi]);
        acc2[mfi][nfi] = MFMA16(al[mfi], bh[nfi], acc2[mfi][nfi]);
      }
  }
#pragma unroll
  for (int mfi = 0; mfi < 4; ++mfi) {
    int col0 = w * 64 + mfi * 16 + (lg << 2);
    f32x4 bv = *(const f32x4*)(bo2 + col0);
#pragma unroll
    for (int nfi = 0; nfi < 2; ++nfi) {
      int row = nfi * 16 + lr;
      U64q ph, pl;
#pragma unroll
      for (int i2 = 0; i2 < 4; ++i2) {
        float x = fmaxf(acc2[mfi][nfi][i2] + bv[i2], 0.f);
        ph.q[i2] = (__bf16)x;
        pl.q[i2] = (__bf16)(x - (float)ph.q[i2]);
      }
      int off = (row * 512 + col0 * 2) ^ ((row & 7) << 4);
      *(unsigned long long*)(h2hi + off) = ph.u;
      *(unsigned long long*)(h2lo + off) = pl.u;
    }
  }
  __syncthreads();

  f32x4 acc3[2] = {};
#pragma unroll
  for (int kk = 0; kk < 8; ++kk) {
    int colp = w * 16 + lr;
    int gb = colp * 512 + kk * 64 + (lg << 4);
    bf16x8 a3h = *(const bf16x8*)(o3h + gb);
    bf16x8 a3l = *(const bf16x8*)(o3l + gb);
#pragma unroll
    for (int nfi = 0; nfi < 2; ++nfi) {
      int row = nfi * 16 + lr;
      int off = (row * 512 + kk * 64 + (lg << 4)) ^ ((row & 7) << 4);
      bf16x8 b3h = *(const bf16x8*)(h2hi + off);
      bf16x8 b3l = *(const bf16x8*)(h2lo + off);
      acc3[nfi] = MFMA16(a3h, b3h, acc3[nfi]);
      acc3[nfi] = MFMA16(a3h, b3l, acc3[nfi]);
      acc3[nfi] = MFMA16(a3l, b3h, acc3[nfi]);
    }
  }
#pragma unroll
  for (int nfi = 0; nfi < 2; ++nfi) {
    int row = nfi * 16 + lr;
    int col0 = w * 16 + (lg << 2);
    f32x4 bv = *(const f32x4*)(bo3 + col0);
    f32x4 iv = *(const f32x4*)(inputs + (r0 + row) * 64 + col0);
    f32x4 o;
#pragma unroll
    for (int i2 = 0; i2 < 4; ++i2) o[i2] = acc3[nfi][i2] + bv[i2] + iv[i2];
    *(f32x4*)(out + (r0 + row) * 64 + col0) = o;
  }
}

// ===========================================================================
extern "C" void kernel_launch(void* const* d_in, const int* in_sizes, int n_in,
                              void* d_out, int out_size, void* d_ws, size_t ws_size,
                              hipStream_t stream) {
  (void)in_sizes; (void)n_in; (void)out_size;
  if (ws_size < (size_t)WS_NEED) return;

  const float* inputs   = (const float*)d_in[0];
  const float* rel_type = (const float*)d_in[1];
  const float* W1  = (const float*)d_in[4];
  const float* b1  = (const float*)d_in[5];
  const float* W2  = (const float*)d_in[6];
  const float* b2  = (const float*)d_in[7];
  const float* Wo1 = (const float*)d_in[8];
  const float* bo1 = (const float*)d_in[9];
  const float* Wo2 = (const float*)d_in[10];
  const float* bo2 = (const float*)d_in[11];
  const float* Wo3 = (const float*)d_in[12];
  const float* bo3 = (const float*)d_in[13];

  char* ws = (char*)d_ws;
  float*  agg  = (float*)(ws + WS_AGG);
  __bf16* msgs = (__bf16*)(ws + WS_MSGS);
  float*  out  = (float*)d_out;

  k0_convert<<<dim3(1216), dim3(256), 0, stream>>>(W1, W2, Wo1, Wo2, Wo3, ws);
  k0b_hr<<<dim3(64), dim3(256), 0, stream>>>(inputs, b1, ws, ws + WS_HR);
  k1_edge<<<dim3(2016), dim3(256), 0, stream>>>(inputs, rel_type, b2, ws, msgs);
  k2_agg<<<dim3(1024), dim3(256), 0, stream>>>((const unsigned short*)msgs, agg);
  k3_node<<<dim3(128), dim3(256), 0, stream>>>(inputs, agg, ws, bo1, bo2, bo3, out);
}

// Round 9
// 282.443 us; speedup vs baseline: 1.3134x; 1.1581x over previous
//
#include <hip/hip_runtime.h>
#include <stdint.h>

// ---------------------------------------------------------------------------
// NRI-style graph block, v9: WEIGHT-RESIDENT kap-specialized edge MLP.
// R1-R8 all ~300us, pipes <25%: per-wave weight re-reads (2GB L2) on long
// dependent chains at ~2 waves/SIMD real occupancy. v9: block = (kap,b,n);
// W1send[kap] frags in REGISTERS, W2[kap] staged to LDS ONCE; zero weight
// loads in steady state. In-block shuffle-reduce -> atomicAdd into agg
// (msgs + k2 deleted; ws = 10 MB).
//   K0 : weights fp32->bf16 (+ zero agg: atomics accumulate per launch)
//   K0b: hr[b,r,kap,:] = W1recv @ x_r + b1  (rank-1 receiver part, bf16)
//   K1 : per-(kap,receiver) edge MLP, weight-resident, atomic reduce
//   K3 : node MLP split-bf16 (hi+lo 3-term MFMA) + residual
// ---------------------------------------------------------------------------

typedef __attribute__((ext_vector_type(8))) __bf16 bf16x8;
typedef __attribute__((ext_vector_type(4))) float  f32x4;
typedef __attribute__((ext_vector_type(8))) short  short8;

#define MFMA16(a, b, c) __builtin_amdgcn_mfma_f32_16x16x32_bf16((a), (b), (c), 0, 0, 0)

union U64q { unsigned long long u; __bf16 q[4]; };

static __device__ __forceinline__ unsigned short bfb(__bf16 x) {
  union { __bf16 b; unsigned short u; } c; c.b = x; return c.u;
}

// ---- ws layout (bytes) ----
#define WS_W1    0          // [4][256][128] bf16  (262144)
#define WS_W2    262144     // [4][64][256] bf16   (131072)
#define WS_O1H   393216     // [256][128] bf16 hi  (65536)
#define WS_O1L   458752
#define WS_O2H   524288     // [256][256] bf16     (131072)
#define WS_O2L   655360
#define WS_O3H   786432     // [64][256] bf16      (32768)
#define WS_O3L   819200
#define WS_AGG   1048576    // [B*N][64] f32       (1048576) -- atomic target
#define WS_HR    2097152    // [64][64][4][256] bf16 (8388608)
#define WS_NEED  10485760   // 10 MB

// ===========================================================================
// K0: weight conversion + agg zero (573440 threads = 2240 blocks x 256)
// ===========================================================================
__global__ __launch_bounds__(256) void k0_convert(
    const float* __restrict__ W1, const float* __restrict__ W2,
    const float* __restrict__ Wo1, const float* __restrict__ Wo2,
    const float* __restrict__ Wo3, char* __restrict__ ws) {
  int i = blockIdx.x * 256 + threadIdx.x;
  __bf16* w1  = (__bf16*)(ws + WS_W1);
  __bf16* w2  = (__bf16*)(ws + WS_W2);
  __bf16* o1h = (__bf16*)(ws + WS_O1H);
  __bf16* o1l = (__bf16*)(ws + WS_O1L);
  __bf16* o2h = (__bf16*)(ws + WS_O2H);
  __bf16* o2l = (__bf16*)(ws + WS_O2L);
  __bf16* o3h = (__bf16*)(ws + WS_O3H);
  __bf16* o3l = (__bf16*)(ws + WS_O3L);
  if (i < 131072) { w1[i] = (__bf16)W1[i]; return; }
  i -= 131072;
  if (i < 65536) { w2[i] = (__bf16)W2[i]; return; }
  i -= 65536;
  if (i < 32768) { float v = Wo1[i]; __bf16 h = (__bf16)v; o1h[i] = h; o1l[i] = (__bf16)(v - (float)h); return; }
  i -= 32768;
  if (i < 65536) { float v = Wo2[i]; __bf16 h = (__bf16)v; o2h[i] = h; o2l[i] = (__bf16)(v - (float)h); return; }
  i -= 65536;
  if (i < 16384) { float v = Wo3[i]; __bf16 h = (__bf16)v; o3h[i] = h; o3l[i] = (__bf16)(v - (float)h); return; }
  i -= 16384;
  if (i < 262144) { ((float*)(ws + WS_AGG))[i] = 0.f; return; }
}

// ===========================================================================
// K0b: hr[b][r][kap][col] = W1recv[kap][col][:]@inputs[b,r,:] + b1[kap][col]
// ===========================================================================
__global__ __launch_bounds__(256) void k0b_hr(
    const float* __restrict__ inputs, const float* __restrict__ b1g,
    const char* __restrict__ wsr, char* __restrict__ hrout) {
  const int b = blockIdx.x;
  const int tid = threadIdx.x, l = tid & 63, w = tid >> 6;  // w = kap
  const int lg = l >> 4, lr = l & 15;

  bf16x8 bfr[4][2];
#pragma unroll
  for (int nt = 0; nt < 4; ++nt)
#pragma unroll
    for (int kc = 0; kc < 2; ++kc) {
      const float* p = inputs + ((size_t)b * 64 + nt * 16 + lr) * 64 + kc * 32 + lg * 8;
      f32x4 v0 = *(const f32x4*)p, v1 = *(const f32x4*)(p + 4);
      bf16x8 t;
#pragma unroll
      for (int j = 0; j < 4; ++j) { t[j] = (__bf16)v0[j]; t[4 + j] = (__bf16)v1[j]; }
      bfr[nt][kc] = t;
    }

  const char* w1 = wsr + WS_W1;
#pragma unroll 1
  for (int cb = 0; cb < 4; ++cb) {
    f32x4 acc[4][4] = {};
#pragma unroll
    for (int kc = 0; kc < 2; ++kc)
#pragma unroll
      for (int mt = 0; mt < 4; ++mt) {
        int col = w * 256 + cb * 64 + mt * 16 + lr;
        bf16x8 af = *(const bf16x8*)(w1 + (col << 8) + kc * 64 + (lg << 4));
#pragma unroll
        for (int nt = 0; nt < 4; ++nt)
          acc[mt][nt] = MFMA16(af, bfr[nt][kc], acc[mt][nt]);
      }
#pragma unroll
    for (int mt = 0; mt < 4; ++mt) {
      int col0 = cb * 64 + mt * 16 + (lg << 2);
      f32x4 bv = *(const f32x4*)(b1g + w * 256 + col0);
#pragma unroll
      for (int nt = 0; nt < 4; ++nt) {
        int r = nt * 16 + lr;
        U64q pk;
#pragma unroll
        for (int i2 = 0; i2 < 4; ++i2) pk.q[i2] = (__bf16)(acc[mt][nt][i2] + bv[i2]);
        *(unsigned long long*)(hrout + ((((size_t)b * 64 + r) * 4 + w) * 256 + col0) * 2) = pk.u;
      }
    }
  }
}

// ===========================================================================
// K1 v9: block = (kap, b, n). 256 thr / 4 waves. 63 edges + 1 pad slot.
// Prologue: W2[kap] -> LDS (32KB swz, once); send feats -> regs (bs, 32 reg);
// G1 per col-half: W1send frags (16 reg) -> acc1[2][4] -> h1half LDS (16KB).
// G2 per half: A from W2-LDS, B from h1 -> acc2[2][2] accum across halves.
// Gate by rel_type, shuffle-reduce over slots, atomicAdd -> agg[b,n,:].
// LDS 48KB (3 blocks/CU). Barriers: 1 + 2x2 = 5.
// ===========================================================================
__global__ __launch_bounds__(256) void k1_edge(
    const float* __restrict__ inputs, const float* __restrict__ rel_type,
    const float* __restrict__ b2g, const char* __restrict__ wsr,
    float* __restrict__ agg) {
  __shared__ char sm[49152];
  char* w2S = sm;            // [64 feats][512B] bf16, byte ^= ((feat&7)<<4)
  char* h1S = sm + 32768;    // [64 slots][256B] bf16 (one col-half), swz

  const int tid = threadIdx.x;
  const int bid = blockIdx.x;
  const int kap = bid >> 12;            // grid = 4 * 4096
  const int x   = bid & 4095;
  const int b = x >> 6, n = x & 63;
  const int l = tid & 63, w = tid >> 6;
  const int lg = l >> 4, lr = l & 15;
  const int wm = w >> 1, wn = w & 1;    // G2 grid: 2m (feat half) x 2n (slot half)

  // ---- prologue: stage W2[kap] -> LDS (swizzled) ----
  {
    const char* src = wsr + WS_W2 + kap * 32768;
#pragma unroll
    for (int it = 0; it < 8; ++it) {
      int u = tid + it * 256;          // 0..2047 16B units; feat = u>>5
      short8 v = *(const short8*)(src + u * 16);
      *(short8*)(w2S + ((u * 16) ^ (((u >> 5) & 7) << 4))) = v;
    }
  }

  // ---- send-feat B-frags (all 64 slots, kept in regs) ----
  bf16x8 bs[4][2];
#pragma unroll
  for (int nf = 0; nf < 4; ++nf) {
    int slot = nf * 16 + lr;
    int j = slot < 63 ? slot : 62;     // pad slot dups j=62 (rt gate = 0)
    int s = j + (j >= n ? 1 : 0);
#pragma unroll
    for (int kc = 0; kc < 2; ++kc) {
      const float* p = inputs + ((size_t)b * 64 + s) * 64 + kc * 32 + lg * 8;
      f32x4 v0 = *(const f32x4*)p, v1 = *(const f32x4*)(p + 4);
      bf16x8 t;
#pragma unroll
      for (int jj = 0; jj < 4; ++jj) { t[jj] = (__bf16)v0[jj]; t[4 + jj] = (__bf16)v1[jj]; }
      bs[nf][kc] = t;
    }
  }

  // rel_type gates for this wave's G2 slots (pad -> 0)
  float rt[2];
#pragma unroll
  for (int nf2 = 0; nf2 < 2; ++nf2) {
    int slot = wn * 32 + nf2 * 16 + lr;
    rt[nf2] = (slot < 63) ? rel_type[((size_t)b * 4032 + n * 63 + slot) * 4 + kap] : 0.f;
  }
  // b2 quads for this wave's feats
  f32x4 bv2[2];
#pragma unroll
  for (int mf2 = 0; mf2 < 2; ++mf2)
    bv2[mf2] = *(const f32x4*)(b2g + kap * 64 + wm * 32 + mf2 * 16 + (lg << 2));

  const char* w1p = wsr + WS_W1;
  const char* hrp = wsr + WS_HR;
  __syncthreads();   // W2 staged

  f32x4 acc2[2][2] = {};               // [mf2][nf2], accum across halves

#pragma unroll 1
  for (int mh = 0; mh < 2; ++mh) {
    // ===== G1 half: h1 cols [mh*128,+128); wave w covers 32 cols =====
    bf16x8 W1f[2][2];                  // [kc][mt]
#pragma unroll
    for (int kc = 0; kc < 2; ++kc)
#pragma unroll
      for (int mt = 0; mt < 2; ++mt) {
        int colp = mh * 128 + w * 32 + mt * 16 + lr;
        W1f[kc][mt] = *(const bf16x8*)(w1p + (((size_t)kap * 256 + colp) << 8) + 128 + kc * 64 + (lg << 4));
      }
    f32x4 acc1[2][4] = {};
#pragma unroll
    for (int kc = 0; kc < 2; ++kc)
#pragma unroll
      for (int mt = 0; mt < 2; ++mt)
#pragma unroll
        for (int nf = 0; nf < 4; ++nf)
          acc1[mt][nf] = MFMA16(W1f[kc][mt], bs[nf][kc], acc1[mt][nf]);

    // epilogue: + hr (recv part incl b1), relu, bf16 -> h1S
#pragma unroll
    for (int mt = 0; mt < 2; ++mt) {
      int col0 = mh * 128 + w * 32 + mt * 16 + (lg << 2);
      int lc   = w * 32 + mt * 16 + (lg << 2);       // col within half
      U64q hv;
      hv.u = *(const unsigned long long*)(hrp + ((((size_t)b * 64 + n) * 4 + kap) * 256 + col0) * 2);
#pragma unroll
      for (int nf = 0; nf < 4; ++nf) {
        int slot = nf * 16 + lr;
        U64q pk;
#pragma unroll
        for (int i2 = 0; i2 < 4; ++i2)
          pk.q[i2] = (__bf16)fmaxf(acc1[mt][nf][i2] + (float)hv.q[i2], 0.f);
        int off = (slot * 256 + lc * 2) ^ ((slot & 7) << 4);
        *(unsigned long long*)(h1S + off) = pk.u;
      }
    }
    __syncthreads();   // h1 half ready

    // ===== G2 partial: K window [mh*128,+128) =====
#pragma unroll
    for (int kc2 = 0; kc2 < 4; ++kc2) {
      bf16x8 a2[2], b2f[2];
#pragma unroll
      for (int mf2 = 0; mf2 < 2; ++mf2) {
        int feat = wm * 32 + mf2 * 16 + lr;
        int kb = (mh * 128 + kc2 * 32 + lg * 8) * 2;
        a2[mf2] = *(const bf16x8*)(w2S + ((feat * 512 + kb) ^ ((feat & 7) << 4)));
      }
#pragma unroll
      for (int nf2 = 0; nf2 < 2; ++nf2) {
        int slot = wn * 32 + nf2 * 16 + lr;
        int kb = (kc2 * 32 + lg * 8) * 2;
        b2f[nf2] = *(const bf16x8*)(h1S + ((slot * 256 + kb) ^ ((slot & 7) << 4)));
      }
#pragma unroll
      for (int mf2 = 0; mf2 < 2; ++mf2)
#pragma unroll
        for (int nf2 = 0; nf2 < 2; ++nf2)
          acc2[mf2][nf2] = MFMA16(a2[mf2], b2f[nf2], acc2[mf2][nf2]);
    }
    __syncthreads();   // h1 consumed before next half overwrites
  }

  // ---- gate + reduce over slots -> atomicAdd agg[b,n,:] ----
  float s[2][4];
#pragma unroll
  for (int mf2 = 0; mf2 < 2; ++mf2)
#pragma unroll
    for (int i2 = 0; i2 < 4; ++i2) {
      float v0 = fmaxf(acc2[mf2][0][i2] + bv2[mf2][i2], 0.f) * rt[0];
      float v1 = fmaxf(acc2[mf2][1][i2] + bv2[mf2][i2], 0.f) * rt[1];
      s[mf2][i2] = v0 + v1;
    }
#pragma unroll
  for (int mask = 1; mask < 16; mask <<= 1)
#pragma unroll
    for (int mf2 = 0; mf2 < 2; ++mf2)
#pragma unroll
      for (int i2 = 0; i2 < 4; ++i2)
        s[mf2][i2] += __shfl_xor(s[mf2][i2], mask);

  if (lr == 0) {
    float* dst = agg + ((size_t)b * 64 + n) * 64;
#pragma unroll
    for (int mf2 = 0; mf2 < 2; ++mf2) {
      int f0 = wm * 32 + mf2 * 16 + (lg << 2);
#pragma unroll
      for (int i2 = 0; i2 < 4; ++i2)
        atomicAdd(dst + f0 + i2, s[mf2][i2]);
    }
  }
}

// ===========================================================================
// K3: node MLP with split-bf16 (hi+lo) 3-term MFMA + residual
// ===========================================================================
__global__ __launch_bounds__(256) void k3_node(
    const float* __restrict__ inputs, const float* __restrict__ agg,
    const char* __restrict__ wsr,
    const float* __restrict__ bo1, const float* __restrict__ bo2,
    const float* __restrict__ bo3, float* __restrict__ out) {
  __shared__ char sm[65536];
  char* augHi = sm;                  // [32][128] bf16 swz
  char* augLo = sm + 8192;
  char* h1hi  = sm + 16384;          // [32][256] bf16 swz
  char* h1lo  = sm + 32768;
  char* h2hi  = sm;                  // reuse aug region after GEMM1
  char* h2lo  = sm + 49152;

  const char* o1h = wsr + WS_O1H;
  const char* o1l = wsr + WS_O1L;
  const char* o2h = wsr + WS_O2H;
  const char* o2l = wsr + WS_O2L;
  const char* o3h = wsr + WS_O3H;
  const char* o3l = wsr + WS_O3L;

  const int tid = threadIdx.x;
  const int l = tid & 63;
  const int w = tid >> 6;
  const int lg = l >> 4, lr = l & 15;
  const int r0 = blockIdx.x * 32;

  for (int it = 0; it < 8; ++it) {
    int u = tid + it * 256;
    int row = u >> 6, up = u & 63;
    int col = up * 2;
    const float* src = (col < 64) ? (inputs + (r0 + row) * 64 + col)
                                  : (agg + (r0 + row) * 64 + (col - 64));
    float2 v = *(const float2*)src;
    __bf16 h0 = (__bf16)v.x, h1v = (__bf16)v.y;
    __bf16 l0 = (__bf16)(v.x - (float)h0), l1 = (__bf16)(v.y - (float)h1v);
    int off = (row * 256 + col * 2) ^ ((row & 7) << 4);
    ushort2 ph; ph.x = bfb(h0); ph.y = bfb(h1v);
    ushort2 pl; pl.x = bfb(l0); pl.y = bfb(l1);
    *(ushort2*)(augHi + off) = ph;
    *(ushort2*)(augLo + off) = pl;
  }
  __syncthreads();

  f32x4 acc[4][2] = {};
#pragma unroll
  for (int kk = 0; kk < 4; ++kk) {
    bf16x8 ah[4], al[4], bh[2], bl[2];
#pragma unroll
    for (int mfi = 0; mfi < 4; ++mfi) {
      int colp = w * 64 + mfi * 16 + lr;
      int gb = colp * 256 + kk * 64 + (lg << 4);
      ah[mfi] = *(const bf16x8*)(o1h + gb);
      al[mfi] = *(const bf16x8*)(o1l + gb);
    }
#pragma unroll
    for (int nfi = 0; nfi < 2; ++nfi) {
      int row = nfi * 16 + lr;
      int off = (row * 256 + kk * 64 + (lg << 4)) ^ ((row & 7) << 4);
      bh[nfi] = *(const bf16x8*)(augHi + off);
      bl[nfi] = *(const bf16x8*)(augLo + off);
    }
#pragma unroll
    for (int mfi = 0; mfi < 4; ++mfi)
#pragma unroll
      for (int nfi = 0; nfi < 2; ++nfi) {
        acc[mfi][nfi] = MFMA16(ah[mfi], bh[nfi], acc[mfi][nfi]);
        acc[mfi][nfi] = MFMA16(ah[mfi], bl[nfi], acc[mfi][nfi]);
        acc[mfi][nfi] = MFMA16(al[mfi], bh[nfi], acc[mfi][nfi]);
      }
  }
#pragma unroll
  for (int mfi = 0; mfi < 4; ++mfi) {
    int col0 = w * 64 + mfi * 16 + (lg << 2);
    f32x4 bv = *(const f32x4*)(bo1 + col0);
#pragma unroll
    for (int nfi = 0; nfi < 2; ++nfi) {
      int row = nfi * 16 + lr;
      U64q ph, pl;
#pragma unroll
      for (int i2 = 0; i2 < 4; ++i2) {
        float x = fmaxf(acc[mfi][nfi][i2] + bv[i2], 0.f);
        ph.q[i2] = (__bf16)x;
        pl.q[i2] = (__bf16)(x - (float)ph.q[i2]);
      }
      int off = (row * 512 + col0 * 2) ^ ((row & 7) << 4);
      *(unsigned long long*)(h1hi + off) = ph.u;
      *(unsigned long long*)(h1lo + off) = pl.u;
    }
  }
  __syncthreads();

  f32x4 acc2[4][2] = {};
#pragma unroll
  for (int kk = 0; kk < 8; ++kk) {
    bf16x8 ah[4], al[4], bh[2], bl[2];
#pragma unroll
    for (int mfi = 0; mfi < 4; ++mfi) {
      int colp = w * 64 + mfi * 16 + lr;
      int gb = colp * 512 + kk * 64 + (lg << 4);
      ah[mfi] = *(const bf16x8*)(o2h + gb);
      al[mfi] = *(const bf16x8*)(o2l + gb);
    }
#pragma unroll
    for (int nfi = 0; nfi < 2; ++nfi) {
      int row = nfi * 16 + lr;
      int off = (row * 512 + kk * 64 + (lg << 4)) ^ ((row & 7) << 4);
      bh[nfi] = *(const bf16x8*)(h1hi + off);
      bl[nfi] = *(const bf16x8*)(h1lo + off);
    }
#pragma unroll
    for (int mfi = 0; mfi < 4; ++mfi)
#pragma unroll
      for (int nfi = 0; nfi < 2; ++nfi) {
        acc2[mfi][nfi] = MFMA16(ah[mfi], bh[nfi], acc2[mfi][nfi]);
        acc2[mfi][nfi] = MFMA16(ah[mfi], bl[nfi], acc2[mfi][nfi]);
        acc2[mfi][nfi] = MFMA16(al[mfi], bh[nfi], acc2[mfi][nfi]);
      }
  }
#pragma unroll
  for (int mfi = 0; mfi < 4; ++mfi) {
    int col0 = w * 64 + mfi * 16 + (lg << 2);
    f32x4 bv = *(const f32x4*)(bo2 + col0);
#pragma unroll
    for (int nfi = 0; nfi < 2; ++nfi) {
      int row = nfi * 16 + lr;
      U64q ph, pl;
#pragma unroll
      for (int i2 = 0; i2 < 4; ++i2) {
        float x = fmaxf(acc2[mfi][nfi][i2] + bv[i2], 0.f);
        ph.q[i2] = (__bf16)x;
        pl.q[i2] = (__bf16)(x - (float)ph.q[i2]);
      }
      int off = (row * 512 + col0 * 2) ^ ((row & 7) << 4);
      *(unsigned long long*)(h2hi + off) = ph.u;
      *(unsigned long long*)(h2lo + off) = pl.u;
    }
  }
  __syncthreads();

  f32x4 acc3[2] = {};
#pragma unroll
  for (int kk = 0; kk < 8; ++kk) {
    int colp = w * 16 + lr;
    int gb = colp * 512 + kk * 64 + (lg << 4);
    bf16x8 a3h = *(const bf16x8*)(o3h + gb);
    bf16x8 a3l = *(const bf16x8*)(o3l + gb);
#pragma unroll
    for (int nfi = 0; nfi < 2; ++nfi) {
      int row = nfi * 16 + lr;
      int off = (row * 512 + kk * 64 + (lg << 4)) ^ ((row & 7) << 4);
      bf16x8 b3h = *(const bf16x8*)(h2hi + off);
      bf16x8 b3l = *(const bf16x8*)(h2lo + off);
      acc3[nfi] = MFMA16(a3h, b3h, acc3[nfi]);
      acc3[nfi] = MFMA16(a3h, b3l, acc3[nfi]);
      acc3[nfi] = MFMA16(a3l, b3h, acc3[nfi]);
    }
  }
#pragma unroll
  for (int nfi = 0; nfi < 2; ++nfi) {
    int row = nfi * 16 + lr;
    int col0 = w * 16 + (lg << 2);
    f32x4 bv = *(const f32x4*)(bo3 + col0);
    f32x4 iv = *(const f32x4*)(inputs + (r0 + row) * 64 + col0);
    f32x4 o;
#pragma unroll
    for (int i2 = 0; i2 < 4; ++i2) o[i2] = acc3[nfi][i2] + bv[i2] + iv[i2];
    *(f32x4*)(out + (r0 + row) * 64 + col0) = o;
  }
}

// ===========================================================================
extern "C" void kernel_launch(void* const* d_in, const int* in_sizes, int n_in,
                              void* d_out, int out_size, void* d_ws, size_t ws_size,
                              hipStream_t stream) {
  (void)in_sizes; (void)n_in; (void)out_size;
  if (ws_size < (size_t)WS_NEED) return;  // 10 MB

  const float* inputs   = (const float*)d_in[0];
  const float* rel_type = (const float*)d_in[1];
  const float* W1  = (const float*)d_in[4];
  const float* b1  = (const float*)d_in[5];
  const float* W2  = (const float*)d_in[6];
  const float* b2  = (const float*)d_in[7];
  const float* Wo1 = (const float*)d_in[8];
  const float* bo1 = (const float*)d_in[9];
  const float* Wo2 = (const float*)d_in[10];
  const float* bo2 = (const float*)d_in[11];
  const float* Wo3 = (const float*)d_in[12];
  const float* bo3 = (const float*)d_in[13];

  char* ws = (char*)d_ws;
  float* agg = (float*)(ws + WS_AGG);
  float* out = (float*)d_out;

  k0_convert<<<dim3(2240), dim3(256), 0, stream>>>(W1, W2, Wo1, Wo2, Wo3, ws);
  k0b_hr<<<dim3(64), dim3(256), 0, stream>>>(inputs, b1, ws, ws + WS_HR);
  k1_edge<<<dim3(16384), dim3(256), 0, stream>>>(inputs, rel_type, b2, ws, agg);
  k3_node<<<dim3(128), dim3(256), 0, stream>>>(inputs, agg, ws, bo1, bo2, bo3, out);
}

// Round 10
// 270.316 us; speedup vs baseline: 1.3723x; 1.0449x over previous
//
#include <hip/hip_runtime.h>
#include <stdint.h>

// ---------------------------------------------------------------------------
// NRI-style graph block, v10: ALL-COALESCED weight path.
// R1-R9 invariant (~250-350us, all pipes <30%): every global MFMA A-frag load
// had lane=row at 256/512B stride -> 64-line fan-out per instr, 4x L2->L1
// over-fetch (GBs/launch), saturating the vector-mem path invisibly.
// v10 = R9 + W1send[kap] staged COALESCED into LDS (single-variable change):
// zero divergent weight loads remain; A-frags via swizzled ds_read_b128.
//   K0 : weights fp32->bf16 (+ zero agg; atomics accumulate per launch)
//   K0b: hr[b,r,kap,:] = W1recv @ x_r + b1  (rank-1 receiver part, bf16)
//   K1 : block=(kap,b,n); W1send+W2 in LDS (64KB) + h1 half (16KB) = 80KB;
//        gather sends->regs; gate; shuffle-reduce; atomicAdd agg.
//   K3 : node MLP split-bf16 (hi+lo 3-term MFMA) + residual
// ---------------------------------------------------------------------------

typedef __attribute__((ext_vector_type(8))) __bf16 bf16x8;
typedef __attribute__((ext_vector_type(4))) float  f32x4;
typedef __attribute__((ext_vector_type(8))) short  short8;

#define MFMA16(a, b, c) __builtin_amdgcn_mfma_f32_16x16x32_bf16((a), (b), (c), 0, 0, 0)

union U64q { unsigned long long u; __bf16 q[4]; };

static __device__ __forceinline__ unsigned short bfb(__bf16 x) {
  union { __bf16 b; unsigned short u; } c; c.b = x; return c.u;
}

// ---- ws layout (bytes) ----
#define WS_W1    0          // [4][256][128] bf16  (262144)
#define WS_W2    262144     // [4][64][256] bf16   (131072)
#define WS_O1H   393216     // [256][128] bf16 hi  (65536)
#define WS_O1L   458752
#define WS_O2H   524288     // [256][256] bf16     (131072)
#define WS_O2L   655360
#define WS_O3H   786432     // [64][256] bf16      (32768)
#define WS_O3L   819200
#define WS_AGG   1048576    // [B*N][64] f32       (1048576) -- atomic target
#define WS_HR    2097152    // [64][64][4][256] bf16 (8388608)
#define WS_NEED  10485760   // 10 MB

// ===========================================================================
// K0: weight conversion + agg zero
// ===========================================================================
__global__ __launch_bounds__(256) void k0_convert(
    const float* __restrict__ W1, const float* __restrict__ W2,
    const float* __restrict__ Wo1, const float* __restrict__ Wo2,
    const float* __restrict__ Wo3, char* __restrict__ ws) {
  int i = blockIdx.x * 256 + threadIdx.x;
  __bf16* w1  = (__bf16*)(ws + WS_W1);
  __bf16* w2  = (__bf16*)(ws + WS_W2);
  __bf16* o1h = (__bf16*)(ws + WS_O1H);
  __bf16* o1l = (__bf16*)(ws + WS_O1L);
  __bf16* o2h = (__bf16*)(ws + WS_O2H);
  __bf16* o2l = (__bf16*)(ws + WS_O2L);
  __bf16* o3h = (__bf16*)(ws + WS_O3H);
  __bf16* o3l = (__bf16*)(ws + WS_O3L);
  if (i < 131072) { w1[i] = (__bf16)W1[i]; return; }
  i -= 131072;
  if (i < 65536) { w2[i] = (__bf16)W2[i]; return; }
  i -= 65536;
  if (i < 32768) { float v = Wo1[i]; __bf16 h = (__bf16)v; o1h[i] = h; o1l[i] = (__bf16)(v - (float)h); return; }
  i -= 32768;
  if (i < 65536) { float v = Wo2[i]; __bf16 h = (__bf16)v; o2h[i] = h; o2l[i] = (__bf16)(v - (float)h); return; }
  i -= 65536;
  if (i < 16384) { float v = Wo3[i]; __bf16 h = (__bf16)v; o3h[i] = h; o3l[i] = (__bf16)(v - (float)h); return; }
  i -= 16384;
  if (i < 262144) { ((float*)(ws + WS_AGG))[i] = 0.f; return; }
}

// ===========================================================================
// K0b: hr[b][r][kap][col] = W1recv[kap][col][:]@inputs[b,r,:] + b1[kap][col]
// ===========================================================================
__global__ __launch_bounds__(256) void k0b_hr(
    const float* __restrict__ inputs, const float* __restrict__ b1g,
    const char* __restrict__ wsr, char* __restrict__ hrout) {
  const int b = blockIdx.x;
  const int tid = threadIdx.x, l = tid & 63, w = tid >> 6;  // w = kap
  const int lg = l >> 4, lr = l & 15;

  bf16x8 bfr[4][2];
#pragma unroll
  for (int nt = 0; nt < 4; ++nt)
#pragma unroll
    for (int kc = 0; kc < 2; ++kc) {
      const float* p = inputs + ((size_t)b * 64 + nt * 16 + lr) * 64 + kc * 32 + lg * 8;
      f32x4 v0 = *(const f32x4*)p, v1 = *(const f32x4*)(p + 4);
      bf16x8 t;
#pragma unroll
      for (int j = 0; j < 4; ++j) { t[j] = (__bf16)v0[j]; t[4 + j] = (__bf16)v1[j]; }
      bfr[nt][kc] = t;
    }

  const char* w1 = wsr + WS_W1;
#pragma unroll 1
  for (int cb = 0; cb < 4; ++cb) {
    f32x4 acc[4][4] = {};
#pragma unroll
    for (int kc = 0; kc < 2; ++kc)
#pragma unroll
      for (int mt = 0; mt < 4; ++mt) {
        int col = w * 256 + cb * 64 + mt * 16 + lr;
        bf16x8 af = *(const bf16x8*)(w1 + (col << 8) + kc * 64 + (lg << 4));
#pragma unroll
        for (int nt = 0; nt < 4; ++nt)
          acc[mt][nt] = MFMA16(af, bfr[nt][kc], acc[mt][nt]);
      }
#pragma unroll
    for (int mt = 0; mt < 4; ++mt) {
      int col0 = cb * 64 + mt * 16 + (lg << 2);
      f32x4 bv = *(const f32x4*)(b1g + w * 256 + col0);
#pragma unroll
      for (int nt = 0; nt < 4; ++nt) {
        int r = nt * 16 + lr;
        U64q pk;
#pragma unroll
        for (int i2 = 0; i2 < 4; ++i2) pk.q[i2] = (__bf16)(acc[mt][nt][i2] + bv[i2]);
        *(unsigned long long*)(hrout + ((((size_t)b * 64 + r) * 4 + w) * 256 + col0) * 2) = pk.u;
      }
    }
  }
}

// ===========================================================================
// K1 v10: block = (kap, b, n). 256 thr / 4 waves. 63 edges + 1 pad slot.
// LDS: w1S [256 h1cols][128B send-K] swz (32K) | w2S [64][512B] swz (32K)
//      | h1S [64 slots][256B col-half] swz (16K)  = 80KB -> 2 blocks/CU.
// ALL weight global loads coalesced (tid-linear). A-frags via ds_read_b128.
// ===========================================================================
__global__ __launch_bounds__(256) void k1_edge(
    const float* __restrict__ inputs, const float* __restrict__ rel_type,
    const float* __restrict__ b2g, const char* __restrict__ wsr,
    float* __restrict__ agg) {
  __shared__ char sm[81920];
  char* w1S = sm;            // [col][128B], byte ^= ((col&7)<<4)
  char* w2S = sm + 32768;    // [feat][512B], byte ^= ((feat&7)<<4)
  char* h1S = sm + 65536;    // [slot][256B], byte ^= ((slot&7)<<4)

  const int tid = threadIdx.x;
  const int bid = blockIdx.x;
  const int kap = bid >> 12;            // grid = 4 * 4096 (same-kap blocks adjacent)
  const int x   = bid & 4095;
  const int b = x >> 6, n = x & 63;
  const int l = tid & 63, w = tid >> 6;
  const int lg = l >> 4, lr = l & 15;
  const int wm = w >> 1, wn = w & 1;    // G2 grid: 2m (feat half) x 2n (slot half)

  // ---- prologue: stage W1send[kap] and W2[kap] -> LDS, coalesced ----
  {
    const char* s1 = wsr + WS_W1 + kap * 65536;   // rows 256B, send half at +128
#pragma unroll
    for (int it = 0; it < 8; ++it) {
      int u = tid + it * 256;          // 0..2047 : col = u>>3, 16B unit = u&7
      int col = u >> 3, kb = (u & 7) * 16;
      short8 v = *(const short8*)(s1 + col * 256 + 128 + kb);
      *(short8*)(w1S + col * 128 + (kb ^ ((col & 7) << 4))) = v;
    }
    const char* s2 = wsr + WS_W2 + kap * 32768;
#pragma unroll
    for (int it = 0; it < 8; ++it) {
      int u = tid + it * 256;          // 0..2047 16B units; feat = u>>5
      short8 v = *(const short8*)(s2 + u * 16);
      *(short8*)(w2S + ((u * 16) ^ (((u >> 5) & 7) << 4))) = v;
    }
  }

  // ---- send-feat B-frags (all 64 slots, kept in regs; inputs[b] L1-hot) ----
  bf16x8 bs[4][2];
#pragma unroll
  for (int nf = 0; nf < 4; ++nf) {
    int slot = nf * 16 + lr;
    int j = slot < 63 ? slot : 62;     // pad slot dups j=62 (rt gate = 0)
    int s = j + (j >= n ? 1 : 0);
#pragma unroll
    for (int kc = 0; kc < 2; ++kc) {
      const float* p = inputs + ((size_t)b * 64 + s) * 64 + kc * 32 + lg * 8;
      f32x4 v0 = *(const f32x4*)p, v1 = *(const f32x4*)(p + 4);
      bf16x8 t;
#pragma unroll
      for (int jj = 0; jj < 4; ++jj) { t[jj] = (__bf16)v0[jj]; t[4 + jj] = (__bf16)v1[jj]; }
      bs[nf][kc] = t;
    }
  }

  // rel_type gates for this wave's G2 slots (pad -> 0)
  float rt[2];
#pragma unroll
  for (int nf2 = 0; nf2 < 2; ++nf2) {
    int slot = wn * 32 + nf2 * 16 + lr;
    rt[nf2] = (slot < 63) ? rel_type[((size_t)b * 4032 + n * 63 + slot) * 4 + kap] : 0.f;
  }
  // b2 quads for this wave's feats
  f32x4 bv2[2];
#pragma unroll
  for (int mf2 = 0; mf2 < 2; ++mf2)
    bv2[mf2] = *(const f32x4*)(b2g + kap * 64 + wm * 32 + mf2 * 16 + (lg << 2));

  const char* hrp = wsr + WS_HR;
  __syncthreads();   // weights staged

  f32x4 acc2[2][2] = {};               // [mf2][nf2], accum across halves

#pragma unroll 1
  for (int mh = 0; mh < 2; ++mh) {
    // ===== G1 half: h1 cols [mh*128,+128); wave w covers 32 cols =====
    // A-frags from LDS w1S (swizzled ds_read_b128)
    bf16x8 W1f[2][2];                  // [kc][mt]
#pragma unroll
    for (int kc = 0; kc < 2; ++kc)
#pragma unroll
      for (int mt = 0; mt < 2; ++mt) {
        int colp = mh * 128 + w * 32 + mt * 16 + lr;
        int kb = kc * 64 + (lg << 4);
        W1f[kc][mt] = *(const bf16x8*)(w1S + colp * 128 + (kb ^ ((colp & 7) << 4)));
      }
    f32x4 acc1[2][4] = {};
#pragma unroll
    for (int kc = 0; kc < 2; ++kc)
#pragma unroll
      for (int mt = 0; mt < 2; ++mt)
#pragma unroll
        for (int nf = 0; nf < 4; ++nf)
          acc1[mt][nf] = MFMA16(W1f[kc][mt], bs[nf][kc], acc1[mt][nf]);

    // epilogue: + hr (recv part incl b1), relu, bf16 -> h1S
#pragma unroll
    for (int mt = 0; mt < 2; ++mt) {
      int col0 = mh * 128 + w * 32 + mt * 16 + (lg << 2);
      int lc   = w * 32 + mt * 16 + (lg << 2);       // col within half
      U64q hv;
      hv.u = *(const unsigned long long*)(hrp + ((((size_t)b * 64 + n) * 4 + kap) * 256 + col0) * 2);
#pragma unroll
      for (int nf = 0; nf < 4; ++nf) {
        int slot = nf * 16 + lr;
        U64q pk;
#pragma unroll
        for (int i2 = 0; i2 < 4; ++i2)
          pk.q[i2] = (__bf16)fmaxf(acc1[mt][nf][i2] + (float)hv.q[i2], 0.f);
        int off = (slot * 256 + lc * 2) ^ ((slot & 7) << 4);
        *(unsigned long long*)(h1S + off) = pk.u;
      }
    }
    __syncthreads();   // h1 half ready

    // ===== G2 partial: K window [mh*128,+128) =====
#pragma unroll
    for (int kc2 = 0; kc2 < 4; ++kc2) {
      bf16x8 a2[2], b2f[2];
#pragma unroll
      for (int mf2 = 0; mf2 < 2; ++mf2) {
        int feat = wm * 32 + mf2 * 16 + lr;
        int kb = (mh * 128 + kc2 * 32 + lg * 8) * 2;
        a2[mf2] = *(const bf16x8*)(w2S + ((feat * 512 + kb) ^ ((feat & 7) << 4)));
      }
#pragma unroll
      for (int nf2 = 0; nf2 < 2; ++nf2) {
        int slot = wn * 32 + nf2 * 16 + lr;
        int kb = (kc2 * 32 + lg * 8) * 2;
        b2f[nf2] = *(const bf16x8*)(h1S + ((slot * 256 + kb) ^ ((slot & 7) << 4)));
      }
#pragma unroll
      for (int mf2 = 0; mf2 < 2; ++mf2)
#pragma unroll
        for (int nf2 = 0; nf2 < 2; ++nf2)
          acc2[mf2][nf2] = MFMA16(a2[mf2], b2f[nf2], acc2[mf2][nf2]);
    }
    __syncthreads();   // h1 consumed before next half overwrites
  }

  // ---- gate + reduce over slots -> atomicAdd agg[b,n,:] ----
  float s[2][4];
#pragma unroll
  for (int mf2 = 0; mf2 < 2; ++mf2)
#pragma unroll
    for (int i2 = 0; i2 < 4; ++i2) {
      float v0 = fmaxf(acc2[mf2][0][i2] + bv2[mf2][i2], 0.f) * rt[0];
      float v1 = fmaxf(acc2[mf2][1][i2] + bv2[mf2][i2], 0.f) * rt[1];
      s[mf2][i2] = v0 + v1;
    }
#pragma unroll
  for (int mask = 1; mask < 16; mask <<= 1)
#pragma unroll
    for (int mf2 = 0; mf2 < 2; ++mf2)
#pragma unroll
      for (int i2 = 0; i2 < 4; ++i2)
        s[mf2][i2] += __shfl_xor(s[mf2][i2], mask);

  if (lr == 0) {
    float* dst = agg + ((size_t)b * 64 + n) * 64;
#pragma unroll
    for (int mf2 = 0; mf2 < 2; ++mf2) {
      int f0 = wm * 32 + mf2 * 16 + (lg << 2);
#pragma unroll
      for (int i2 = 0; i2 < 4; ++i2)
        atomicAdd(dst + f0 + i2, s[mf2][i2]);
    }
  }
}

// ===========================================================================
// K3: node MLP with split-bf16 (hi+lo) 3-term MFMA + residual
// ===========================================================================
__global__ __launch_bounds__(256) void k3_node(
    const float* __restrict__ inputs, const float* __restrict__ agg,
    const char* __restrict__ wsr,
    const float* __restrict__ bo1, const float* __restrict__ bo2,
    const float* __restrict__ bo3, float* __restrict__ out) {
  __shared__ char sm[65536];
  char* augHi = sm;                  // [32][128] bf16 swz
  char* augLo = sm + 8192;
  char* h1hi  = sm + 16384;          // [32][256] bf16 swz
  char* h1lo  = sm + 32768;
  char* h2hi  = sm;                  // reuse aug region after GEMM1
  char* h2lo  = sm + 49152;

  const char* o1h = wsr + WS_O1H;
  const char* o1l = wsr + WS_O1L;
  const char* o2h = wsr + WS_O2H;
  const char* o2l = wsr + WS_O2L;
  const char* o3h = wsr + WS_O3H;
  const char* o3l = wsr + WS_O3L;

  const int tid = threadIdx.x;
  const int l = tid & 63;
  const int w = tid >> 6;
  const int lg = l >> 4, lr = l & 15;
  const int r0 = blockIdx.x * 32;

  for (int it = 0; it < 8; ++it) {
    int u = tid + it * 256;
    int row = u >> 6, up = u & 63;
    int col = up * 2;
    const float* src = (col < 64) ? (inputs + (r0 + row) * 64 + col)
                                  : (agg + (r0 + row) * 64 + (col - 64));
    float2 v = *(const float2*)src;
    __bf16 h0 = (__bf16)v.x, h1v = (__bf16)v.y;
    __bf16 l0 = (__bf16)(v.x - (float)h0), l1 = (__bf16)(v.y - (float)h1v);
    int off = (row * 256 + col * 2) ^ ((row & 7) << 4);
    ushort2 ph; ph.x = bfb(h0); ph.y = bfb(h1v);
    ushort2 pl; pl.x = bfb(l0); pl.y = bfb(l1);
    *(ushort2*)(augHi + off) = ph;
    *(ushort2*)(augLo + off) = pl;
  }
  __syncthreads();

  f32x4 acc[4][2] = {};
#pragma unroll
  for (int kk = 0; kk < 4; ++kk) {
    bf16x8 ah[4], al[4], bh[2], bl[2];
#pragma unroll
    for (int mfi = 0; mfi < 4; ++mfi) {
      int colp = w * 64 + mfi * 16 + lr;
      int gb = colp * 256 + kk * 64 + (lg << 4);
      ah[mfi] = *(const bf16x8*)(o1h + gb);
      al[mfi] = *(const bf16x8*)(o1l + gb);
    }
#pragma unroll
    for (int nfi = 0; nfi < 2; ++nfi) {
      int row = nfi * 16 + lr;
      int off = (row * 256 + kk * 64 + (lg << 4)) ^ ((row & 7) << 4);
      bh[nfi] = *(const bf16x8*)(augHi + off);
      bl[nfi] = *(const bf16x8*)(augLo + off);
    }
#pragma unroll
    for (int mfi = 0; mfi < 4; ++mfi)
#pragma unroll
      for (int nfi = 0; nfi < 2; ++nfi) {
        acc[mfi][nfi] = MFMA16(ah[mfi], bh[nfi], acc[mfi][nfi]);
        acc[mfi][nfi] = MFMA16(ah[mfi], bl[nfi], acc[mfi][nfi]);
        acc[mfi][nfi] = MFMA16(al[mfi], bh[nfi], acc[mfi][nfi]);
      }
  }
#pragma unroll
  for (int mfi = 0; mfi < 4; ++mfi) {
    int col0 = w * 64 + mfi * 16 + (lg << 2);
    f32x4 bv = *(const f32x4*)(bo1 + col0);
#pragma unroll
    for (int nfi = 0; nfi < 2; ++nfi) {
      int row = nfi * 16 + lr;
      U64q ph, pl;
#pragma unroll
      for (int i2 = 0; i2 < 4; ++i2) {
        float x = fmaxf(acc[mfi][nfi][i2] + bv[i2], 0.f);
        ph.q[i2] = (__bf16)x;
        pl.q[i2] = (__bf16)(x - (float)ph.q[i2]);
      }
      int off = (row * 512 + col0 * 2) ^ ((row & 7) << 4);
      *(unsigned long long*)(h1hi + off) = ph.u;
      *(unsigned long long*)(h1lo + off) = pl.u;
    }
  }
  __syncthreads();

  f32x4 acc2[4][2] = {};
#pragma unroll
  for (int kk = 0; kk < 8; ++kk) {
    bf16x8 ah[4], al[4], bh[2], bl[2];
#pragma unroll
    for (int mfi = 0; mfi < 4; ++mfi) {
      int colp = w * 64 + mfi * 16 + lr;
      int gb = colp * 512 + kk * 64 + (lg << 4);
      ah[mfi] = *(const bf16x8*)(o2h + gb);
      al[mfi] = *(const bf16x8*)(o2l + gb);
    }
#pragma unroll
    for (int nfi = 0; nfi < 2; ++nfi) {
      int row = nfi * 16 + lr;
      int off = (row * 512 + kk * 64 + (lg << 4)) ^ ((row & 7) << 4);
      bh[nfi] = *(const bf16x8*)(h1hi + off);
      bl[nfi] = *(const bf16x8*)(h1lo + off);
    }
#pragma unroll
    for (int mfi = 0; mfi < 4; ++mfi)
#pragma unroll
      for (int nfi = 0; nfi < 2; ++nfi) {
        acc2[mfi][nfi] = MFMA16(ah[mfi], bh[nfi], acc2[mfi][nfi]);
        acc2[mfi][nfi] = MFMA16(ah[mfi], bl[nfi], acc2[mfi][nfi]);
        acc2[mfi][nfi] = MFMA16(al[mfi], bh[nfi], acc2[mfi][nfi]);
      }
  }
#pragma unroll
  for (int mfi = 0; mfi < 4; ++mfi) {
    int col0 = w * 64 + mfi * 16 + (lg << 2);
    f32x4 bv = *(const f32x4*)(bo2 + col0);
#pragma unroll
    for (int nfi = 0; nfi < 2; ++nfi) {
      int row = nfi * 16 + lr;
      U64q ph, pl;
#pragma unroll
      for (int i2 = 0; i2 < 4; ++i2) {
        float x = fmaxf(acc2[mfi][nfi][i2] + bv[i2], 0.f);
        ph.q[i2] = (__bf16)x;
        pl.q[i2] = (__bf16)(x - (float)ph.q[i2]);
      }
      int off = (row * 512 + col0 * 2) ^ ((row & 7) << 4);
      *(unsigned long long*)(h2hi + off) = ph.u;
      *(unsigned long long*)(h2lo + off) = pl.u;
    }
  }
  __syncthreads();

  f32x4 acc3[2] = {};
#pragma unroll
  for (int kk = 0; kk < 8; ++kk) {
    int colp = w * 16 + lr;
    int gb = colp * 512 + kk * 64 + (lg << 4);
    bf16x8 a3h = *(const bf16x8*)(o3h + gb);
    bf16x8 a3l = *(const bf16x8*)(o3l + gb);
#pragma unroll
    for (int nfi = 0; nfi < 2; ++nfi) {
      int row = nfi * 16 + lr;
      int off = (row * 512 + kk * 64 + (lg << 4)) ^ ((row & 7) << 4);
      bf16x8 b3h = *(const bf16x8*)(h2hi + off);
      bf16x8 b3l = *(const bf16x8*)(h2lo + off);
      acc3[nfi] = MFMA16(a3h, b3h, acc3[nfi]);
      acc3[nfi] = MFMA16(a3h, b3l, acc3[nfi]);
      acc3[nfi] = MFMA16(a3l, b3h, acc3[nfi]);
    }
  }
#pragma unroll
  for (int nfi = 0; nfi < 2; ++nfi) {
    int row = nfi * 16 + lr;
    int col0 = w * 16 + (lg << 2);
    f32x4 bv = *(const f32x4*)(bo3 + col0);
    f32x4 iv = *(const f32x4*)(inputs + (r0 + row) * 64 + col0);
    f32x4 o;
#pragma unroll
    for (int i2 = 0; i2 < 4; ++i2) o[i2] = acc3[nfi][i2] + bv[i2] + iv[i2];
    *(f32x4*)(out + (r0 + row) * 64 + col0) = o;
  }
}

// ===========================================================================
extern "C" void kernel_launch(void* const* d_in, const int* in_sizes, int n_in,
                              void* d_out, int out_size, void* d_ws, size_t ws_size,
                              hipStream_t stream) {
  (void)in_sizes; (void)n_in; (void)out_size;
  if (ws_size < (size_t)WS_NEED) return;  // 10 MB

  const float* inputs   = (const float*)d_in[0];
  const float* rel_type = (const float*)d_in[1];
  const float* W1  = (const float*)d_in[4];
  const float* b1  = (const float*)d_in[5];
  const float* W2  = (const float*)d_in[6];
  const float* b2  = (const float*)d_in[7];
  const float* Wo1 = (const float*)d_in[8];
  const float* bo1 = (const float*)d_in[9];
  const float* Wo2 = (const float*)d_in[10];
  const float* bo2 = (const float*)d_in[11];
  const float* Wo3 = (const float*)d_in[12];
  const float* bo3 = (const float*)d_in[13];

  char* ws = (char*)d_ws;
  float* agg = (float*)(ws + WS_AGG);
  float* out = (float*)d_out;

  k0_convert<<<dim3(2240), dim3(256), 0, stream>>>(W1, W2, Wo1, Wo2, Wo3, ws);
  k0b_hr<<<dim3(64), dim3(256), 0, stream>>>(inputs, b1, ws, ws + WS_HR);
  k1_edge<<<dim3(16384), dim3(256), 0, stream>>>(inputs, rel_type, b2, ws, agg);
  k3_node<<<dim3(128), dim3(256), 0, stream>>>(inputs, agg, ws, bo1, bo2, bo3, out);
}

// Round 11
// 263.965 us; speedup vs baseline: 1.4053x; 1.0241x over previous
//
#include <hip/hip_runtime.h>
#include <stdint.h>

// ---------------------------------------------------------------------------
// NRI-style graph block, v11: AMORTIZED long blocks + prefetched unit loop.
// R1-R10 diagnosis: many tiny blocks, each paying unamortized LDS staging +
// exposed L3 latency (hr) on its critical path; 2 blocks/CU concurrency ->
// 32+ sequential block-slots/CU. v11: block = (kap, b, 16 receivers); weights
// staged ONCE per 16 units; hr prefetched to regs at unit start (latency
// hidden under G1); 4 blocks/CU total -> 2 sequential rounds.
//   K0 : weights fp32->bf16 (+ zero agg; atomics accumulate per launch)
//   K0b: hr[b,r,kap,:] = W1recv @ x_r + b1  (rank-1 receiver part, bf16)
//   K1 : unit loop over receivers; all-coalesced weight staging (R10);
//        shuffle-reduce; atomicAdd agg.
//   K3 : node MLP split-bf16 (hi+lo 3-term MFMA) + residual
// ---------------------------------------------------------------------------

typedef __attribute__((ext_vector_type(8))) __bf16 bf16x8;
typedef __attribute__((ext_vector_type(4))) float  f32x4;
typedef __attribute__((ext_vector_type(8))) short  short8;

#define MFMA16(a, b, c) __builtin_amdgcn_mfma_f32_16x16x32_bf16((a), (b), (c), 0, 0, 0)

union U64q { unsigned long long u; __bf16 q[4]; };

static __device__ __forceinline__ unsigned short bfb(__bf16 x) {
  union { __bf16 b; unsigned short u; } c; c.b = x; return c.u;
}

// ---- ws layout (bytes) ----
#define WS_W1    0          // [4][256][128] bf16  (262144)
#define WS_W2    262144     // [4][64][256] bf16   (131072)
#define WS_O1H   393216     // [256][128] bf16 hi  (65536)
#define WS_O1L   458752
#define WS_O2H   524288     // [256][256] bf16     (131072)
#define WS_O2L   655360
#define WS_O3H   786432     // [64][256] bf16      (32768)
#define WS_O3L   819200
#define WS_AGG   1048576    // [B*N][64] f32       (1048576) -- atomic target
#define WS_HR    2097152    // [64][64][4][256] bf16 (8388608)
#define WS_NEED  10485760   // 10 MB

// ===========================================================================
// K0: weight conversion + agg zero
// ===========================================================================
__global__ __launch_bounds__(256) void k0_convert(
    const float* __restrict__ W1, const float* __restrict__ W2,
    const float* __restrict__ Wo1, const float* __restrict__ Wo2,
    const float* __restrict__ Wo3, char* __restrict__ ws) {
  int i = blockIdx.x * 256 + threadIdx.x;
  __bf16* w1  = (__bf16*)(ws + WS_W1);
  __bf16* w2  = (__bf16*)(ws + WS_W2);
  __bf16* o1h = (__bf16*)(ws + WS_O1H);
  __bf16* o1l = (__bf16*)(ws + WS_O1L);
  __bf16* o2h = (__bf16*)(ws + WS_O2H);
  __bf16* o2l = (__bf16*)(ws + WS_O2L);
  __bf16* o3h = (__bf16*)(ws + WS_O3H);
  __bf16* o3l = (__bf16*)(ws + WS_O3L);
  if (i < 131072) { w1[i] = (__bf16)W1[i]; return; }
  i -= 131072;
  if (i < 65536) { w2[i] = (__bf16)W2[i]; return; }
  i -= 65536;
  if (i < 32768) { float v = Wo1[i]; __bf16 h = (__bf16)v; o1h[i] = h; o1l[i] = (__bf16)(v - (float)h); return; }
  i -= 32768;
  if (i < 65536) { float v = Wo2[i]; __bf16 h = (__bf16)v; o2h[i] = h; o2l[i] = (__bf16)(v - (float)h); return; }
  i -= 65536;
  if (i < 16384) { float v = Wo3[i]; __bf16 h = (__bf16)v; o3h[i] = h; o3l[i] = (__bf16)(v - (float)h); return; }
  i -= 16384;
  if (i < 262144) { ((float*)(ws + WS_AGG))[i] = 0.f; return; }
}

// ===========================================================================
// K0b: hr[b][r][kap][col] = W1recv[kap][col][:]@inputs[b,r,:] + b1[kap][col]
// ===========================================================================
__global__ __launch_bounds__(256) void k0b_hr(
    const float* __restrict__ inputs, const float* __restrict__ b1g,
    const char* __restrict__ wsr, char* __restrict__ hrout) {
  const int b = blockIdx.x;
  const int tid = threadIdx.x, l = tid & 63, w = tid >> 6;  // w = kap
  const int lg = l >> 4, lr = l & 15;

  bf16x8 bfr[4][2];
#pragma unroll
  for (int nt = 0; nt < 4; ++nt)
#pragma unroll
    for (int kc = 0; kc < 2; ++kc) {
      const float* p = inputs + ((size_t)b * 64 + nt * 16 + lr) * 64 + kc * 32 + lg * 8;
      f32x4 v0 = *(const f32x4*)p, v1 = *(const f32x4*)(p + 4);
      bf16x8 t;
#pragma unroll
      for (int j = 0; j < 4; ++j) { t[j] = (__bf16)v0[j]; t[4 + j] = (__bf16)v1[j]; }
      bfr[nt][kc] = t;
    }

  const char* w1 = wsr + WS_W1;
#pragma unroll 1
  for (int cb = 0; cb < 4; ++cb) {
    f32x4 acc[4][4] = {};
#pragma unroll
    for (int kc = 0; kc < 2; ++kc)
#pragma unroll
      for (int mt = 0; mt < 4; ++mt) {
        int col = w * 256 + cb * 64 + mt * 16 + lr;
        bf16x8 af = *(const bf16x8*)(w1 + (col << 8) + kc * 64 + (lg << 4));
#pragma unroll
        for (int nt = 0; nt < 4; ++nt)
          acc[mt][nt] = MFMA16(af, bfr[nt][kc], acc[mt][nt]);
      }
#pragma unroll
    for (int mt = 0; mt < 4; ++mt) {
      int col0 = cb * 64 + mt * 16 + (lg << 2);
      f32x4 bv = *(const f32x4*)(b1g + w * 256 + col0);
#pragma unroll
      for (int nt = 0; nt < 4; ++nt) {
        int r = nt * 16 + lr;
        U64q pk;
#pragma unroll
        for (int i2 = 0; i2 < 4; ++i2) pk.q[i2] = (__bf16)(acc[mt][nt][i2] + bv[i2]);
        *(unsigned long long*)(hrout + ((((size_t)b * 64 + r) * 4 + w) * 256 + col0) * 2) = pk.u;
      }
    }
  }
}

// ===========================================================================
// K1 v11: block = (kap, b, ngroup of 16 receivers). 256 thr / 4 waves.
// Prologue: W1send[kap], W2[kap] -> LDS coalesced (64KB), once per block.
// Unit loop (16 receivers): bs gather (L1-hot), hv prefetch (regs), rt issue;
// per half {G1 from LDS weights -> h1S; sync; G2; sync}; reduce; atomicAdd.
// LDS: w1S 32K | w2S 32K | h1S 16K = 80KB exactly -> 2 blocks/CU.
// ===========================================================================
__global__ __launch_bounds__(256) void k1_edge(
    const float* __restrict__ inputs, const float* __restrict__ rel_type,
    const float* __restrict__ b2g, const char* __restrict__ wsr,
    float* __restrict__ agg) {
  __shared__ char sm[81920];
  char* w1S = sm;            // [col][128B], byte ^= ((col&7)<<4)
  char* w2S = sm + 32768;    // [feat][512B], byte ^= ((feat&7)<<4)
  char* h1S = sm + 65536;    // [slot][256B], byte ^= ((slot&7)<<4)

  const int tid = threadIdx.x;
  const int bid = blockIdx.x;
  const int kap = bid >> 8;             // grid = 4 * 64 * 4 = 1024
  const int rem = bid & 255;
  const int b   = rem >> 2;
  const int n0  = (rem & 3) << 4;
  const int l = tid & 63, w = tid >> 6;
  const int lg = l >> 4, lr = l & 15;
  const int wm = w >> 1, wn = w & 1;    // G2 grid: 2m (feat half) x 2n (slot half)

  // ---- prologue: stage W1send[kap] and W2[kap] -> LDS, coalesced ----
  {
    const char* s1 = wsr + WS_W1 + kap * 65536;   // rows 256B, send half at +128
#pragma unroll
    for (int it = 0; it < 8; ++it) {
      int u = tid + it * 256;          // 0..2047 : col = u>>3, 16B unit = u&7
      int col = u >> 3, kb = (u & 7) * 16;
      short8 v = *(const short8*)(s1 + col * 256 + 128 + kb);
      *(short8*)(w1S + col * 128 + (kb ^ ((col & 7) << 4))) = v;
    }
    const char* s2 = wsr + WS_W2 + kap * 32768;
#pragma unroll
    for (int it = 0; it < 8; ++it) {
      int u = tid + it * 256;          // 0..2047 16B units; feat = u>>5
      short8 v = *(const short8*)(s2 + u * 16);
      *(short8*)(w2S + ((u * 16) ^ (((u >> 5) & 7) << 4))) = v;
    }
  }

  // b2 quads for this wave's feats (constant per block)
  f32x4 bv2[2];
#pragma unroll
  for (int mf2 = 0; mf2 < 2; ++mf2)
    bv2[mf2] = *(const f32x4*)(b2g + kap * 64 + wm * 32 + mf2 * 16 + (lg << 2));

  const char* hrp = wsr + WS_HR;
  const float* inpB = inputs + (size_t)b * 4096;
  __syncthreads();   // weights staged

#pragma unroll 1
  for (int u = 0; u < 16; ++u) {
    const int n = n0 + u;

    // ---- send-feat B-frags (inputs[b] L1-hot after unit 0) ----
    bf16x8 bs[4][2];
#pragma unroll
    for (int nf = 0; nf < 4; ++nf) {
      int slot = nf * 16 + lr;
      int j = slot < 63 ? slot : 62;   // pad slot dups j=62 (rt gate = 0)
      int s = j + (j >= n ? 1 : 0);
#pragma unroll
      for (int kc = 0; kc < 2; ++kc) {
        const float* p = inpB + s * 64 + kc * 32 + lg * 8;
        f32x4 v0 = *(const f32x4*)p, v1 = *(const f32x4*)(p + 4);
        bf16x8 t;
#pragma unroll
        for (int jj = 0; jj < 4; ++jj) { t[jj] = (__bf16)v0[jj]; t[4 + jj] = (__bf16)v1[jj]; }
        bs[nf][kc] = t;
      }
    }

    // ---- hv prefetch: 4 x 8B of hr (L3) -- consumed after G1 MFMAs ----
    unsigned long long hvp[2][2];
    {
      const char* hb = hrp + (((size_t)(b * 64 + n)) * 4 + kap) * 512;
#pragma unroll
      for (int mh = 0; mh < 2; ++mh)
#pragma unroll
        for (int mt = 0; mt < 2; ++mt) {
          int col0 = mh * 128 + w * 32 + mt * 16 + (lg << 2);
          hvp[mh][mt] = *(const unsigned long long*)(hb + col0 * 2);
        }
    }

    // ---- rel_type gates (issued early, consumed at reduce) ----
    float rt[2];
#pragma unroll
    for (int nf2 = 0; nf2 < 2; ++nf2) {
      int slot = wn * 32 + nf2 * 16 + lr;
      rt[nf2] = (slot < 63) ? rel_type[((size_t)b * 4032 + n * 63 + slot) * 4 + kap] : 0.f;
    }

    f32x4 acc2[2][2] = {};             // [mf2][nf2], accum across halves

#pragma unroll 1
    for (int mh = 0; mh < 2; ++mh) {
      // ===== G1 half: h1 cols [mh*128,+128); wave w covers 32 cols =====
      bf16x8 W1f[2][2];                // [kc][mt]
#pragma unroll
      for (int kc = 0; kc < 2; ++kc)
#pragma unroll
        for (int mt = 0; mt < 2; ++mt) {
          int colp = mh * 128 + w * 32 + mt * 16 + lr;
          int kb = kc * 64 + (lg << 4);
          W1f[kc][mt] = *(const bf16x8*)(w1S + colp * 128 + (kb ^ ((colp & 7) << 4)));
        }
      f32x4 acc1[2][4] = {};
#pragma unroll
      for (int kc = 0; kc < 2; ++kc)
#pragma unroll
        for (int mt = 0; mt < 2; ++mt)
#pragma unroll
          for (int nf = 0; nf < 4; ++nf)
            acc1[mt][nf] = MFMA16(W1f[kc][mt], bs[nf][kc], acc1[mt][nf]);

      // epilogue: + hv (recv part incl b1), relu, bf16 -> h1S
#pragma unroll
      for (int mt = 0; mt < 2; ++mt) {
        int lc = w * 32 + mt * 16 + (lg << 2);       // col within half
        U64q hv; hv.u = hvp[mh][mt];
#pragma unroll
        for (int nf = 0; nf < 4; ++nf) {
          int slot = nf * 16 + lr;
          U64q pk;
#pragma unroll
          for (int i2 = 0; i2 < 4; ++i2)
            pk.q[i2] = (__bf16)fmaxf(acc1[mt][nf][i2] + (float)hv.q[i2], 0.f);
          int off = (slot * 256 + lc * 2) ^ ((slot & 7) << 4);
          *(unsigned long long*)(h1S + off) = pk.u;
        }
      }
      __syncthreads();   // h1 half ready

      // ===== G2 partial: K window [mh*128,+128) =====
#pragma unroll
      for (int kc2 = 0; kc2 < 4; ++kc2) {
        bf16x8 a2[2], b2f[2];
#pragma unroll
        for (int mf2 = 0; mf2 < 2; ++mf2) {
          int feat = wm * 32 + mf2 * 16 + lr;
          int kb = (mh * 128 + kc2 * 32 + lg * 8) * 2;
          a2[mf2] = *(const bf16x8*)(w2S + ((feat * 512 + kb) ^ ((feat & 7) << 4)));
        }
#pragma unroll
        for (int nf2 = 0; nf2 < 2; ++nf2) {
          int slot = wn * 32 + nf2 * 16 + lr;
          int kb = (kc2 * 32 + lg * 8) * 2;
          b2f[nf2] = *(const bf16x8*)(h1S + ((slot * 256 + kb) ^ ((slot & 7) << 4)));
        }
#pragma unroll
        for (int mf2 = 0; mf2 < 2; ++mf2)
#pragma unroll
          for (int nf2 = 0; nf2 < 2; ++nf2)
            acc2[mf2][nf2] = MFMA16(a2[mf2], b2f[nf2], acc2[mf2][nf2]);
      }
      __syncthreads();   // h1 consumed before next half / next unit overwrites
    }

    // ---- gate + reduce over slots -> atomicAdd agg[b,n,:] ----
    float s[2][4];
#pragma unroll
    for (int mf2 = 0; mf2 < 2; ++mf2)
#pragma unroll
      for (int i2 = 0; i2 < 4; ++i2) {
        float v0 = fmaxf(acc2[mf2][0][i2] + bv2[mf2][i2], 0.f) * rt[0];
        float v1 = fmaxf(acc2[mf2][1][i2] + bv2[mf2][i2], 0.f) * rt[1];
        s[mf2][i2] = v0 + v1;
      }
#pragma unroll
    for (int mask = 1; mask < 16; mask <<= 1)
#pragma unroll
      for (int mf2 = 0; mf2 < 2; ++mf2)
#pragma unroll
        for (int i2 = 0; i2 < 4; ++i2)
          s[mf2][i2] += __shfl_xor(s[mf2][i2], mask);

    if (lr == 0) {
      float* dst = agg + ((size_t)b * 64 + n) * 64;
#pragma unroll
      for (int mf2 = 0; mf2 < 2; ++mf2) {
        int f0 = wm * 32 + mf2 * 16 + (lg << 2);
#pragma unroll
        for (int i2 = 0; i2 < 4; ++i2)
          atomicAdd(dst + f0 + i2, s[mf2][i2]);
      }
    }
  }
}

// ===========================================================================
// K3: node MLP with split-bf16 (hi+lo) 3-term MFMA + residual
// ===========================================================================
__global__ __launch_bounds__(256) void k3_node(
    const float* __restrict__ inputs, const float* __restrict__ agg,
    const char* __restrict__ wsr,
    const float* __restrict__ bo1, const float* __restrict__ bo2,
    const float* __restrict__ bo3, float* __restrict__ out) {
  __shared__ char sm[65536];
  char* augHi = sm;                  // [32][128] bf16 swz
  char* augLo = sm + 8192;
  char* h1hi  = sm + 16384;          // [32][256] bf16 swz
  char* h1lo  = sm + 32768;
  char* h2hi  = sm;                  // reuse aug region after GEMM1
  char* h2lo  = sm + 49152;

  const char* o1h = wsr + WS_O1H;
  const char* o1l = wsr + WS_O1L;
  const char* o2h = wsr + WS_O2H;
  const char* o2l = wsr + WS_O2L;
  const char* o3h = wsr + WS_O3H;
  const char* o3l = wsr + WS_O3L;

  const int tid = threadIdx.x;
  const int l = tid & 63;
  const int w = tid >> 6;
  const int lg = l >> 4, lr = l & 15;
  const int r0 = blockIdx.x * 32;

  for (int it = 0; it < 8; ++it) {
    int u = tid + it * 256;
    int row = u >> 6, up = u & 63;
    int col = up * 2;
    const float* src = (col < 64) ? (inputs + (r0 + row) * 64 + col)
                                  : (agg + (r0 + row) * 64 + (col - 64));
    float2 v = *(const float2*)src;
    __bf16 h0 = (__bf16)v.x, h1v = (__bf16)v.y;
    __bf16 l0 = (__bf16)(v.x - (float)h0), l1 = (__bf16)(v.y - (float)h1v);
    int off = (row * 256 + col * 2) ^ ((row & 7) << 4);
    ushort2 ph; ph.x = bfb(h0); ph.y = bfb(h1v);
    ushort2 pl; pl.x = bfb(l0); pl.y = bfb(l1);
    *(ushort2*)(augHi + off) = ph;
    *(ushort2*)(augLo + off) = pl;
  }
  __syncthreads();

  f32x4 acc[4][2] = {};
#pragma unroll
  for (int kk = 0; kk < 4; ++kk) {
    bf16x8 ah[4], al[4], bh[2], bl[2];
#pragma unroll
    for (int mfi = 0; mfi < 4; ++mfi) {
      int colp = w * 64 + mfi * 16 + lr;
      int gb = colp * 256 + kk * 64 + (lg << 4);
      ah[mfi] = *(const bf16x8*)(o1h + gb);
      al[mfi] = *(const bf16x8*)(o1l + gb);
    }
#pragma unroll
    for (int nfi = 0; nfi < 2; ++nfi) {
      int row = nfi * 16 + lr;
      int off = (row * 256 + kk * 64 + (lg << 4)) ^ ((row & 7) << 4);
      bh[nfi] = *(const bf16x8*)(augHi + off);
      bl[nfi] = *(const bf16x8*)(augLo + off);
    }
#pragma unroll
    for (int mfi = 0; mfi < 4; ++mfi)
#pragma unroll
      for (int nfi = 0; nfi < 2; ++nfi) {
        acc[mfi][nfi] = MFMA16(ah[mfi], bh[nfi], acc[mfi][nfi]);
        acc[mfi][nfi] = MFMA16(ah[mfi], bl[nfi], acc[mfi][nfi]);
        acc[mfi][nfi] = MFMA16(al[mfi], bh[nfi], acc[mfi][nfi]);
      }
  }
#pragma unroll
  for (int mfi = 0; mfi < 4; ++mfi) {
    int col0 = w * 64 + mfi * 16 + (lg << 2);
    f32x4 bv = *(const f32x4*)(bo1 + col0);
#pragma unroll
    for (int nfi = 0; nfi < 2; ++nfi) {
      int row = nfi * 16 + lr;
      U64q ph, pl;
#pragma unroll
      for (int i2 = 0; i2 < 4; ++i2) {
        float x = fmaxf(acc[mfi][nfi][i2] + bv[i2], 0.f);
        ph.q[i2] = (__bf16)x;
        pl.q[i2] = (__bf16)(x - (float)ph.q[i2]);
      }
      int off = (row * 512 + col0 * 2) ^ ((row & 7) << 4);
      *(unsigned long long*)(h1hi + off) = ph.u;
      *(unsigned long long*)(h1lo + off) = pl.u;
    }
  }
  __syncthreads();

  f32x4 acc2[4][2] = {};
#pragma unroll
  for (int kk = 0; kk < 8; ++kk) {
    bf16x8 ah[4], al[4], bh[2], bl[2];
#pragma unroll
    for (int mfi = 0; mfi < 4; ++mfi) {
      int colp = w * 64 + mfi * 16 + lr;
      int gb = colp * 512 + kk * 64 + (lg << 4);
      ah[mfi] = *(const bf16x8*)(o2h + gb);
      al[mfi] = *(const bf16x8*)(o2l + gb);
    }
#pragma unroll
    for (int nfi = 0; nfi < 2; ++nfi) {
      int row = nfi * 16 + lr;
      int off = (row * 512 + kk * 64 + (lg << 4)) ^ ((row & 7) << 4);
      bh[nfi] = *(const bf16x8*)(h1hi + off);
      bl[nfi] = *(const bf16x8*)(h1lo + off);
    }
#pragma unroll
    for (int mfi = 0; mfi < 4; ++mfi)
#pragma unroll
      for (int nfi = 0; nfi < 2; ++nfi) {
        acc2[mfi][nfi] = MFMA16(ah[mfi], bh[nfi], acc2[mfi][nfi]);
        acc2[mfi][nfi] = MFMA16(ah[mfi], bl[nfi], acc2[mfi][nfi]);
        acc2[mfi][nfi] = MFMA16(al[mfi], bh[nfi], acc2[mfi][nfi]);
      }
  }
#pragma unroll
  for (int mfi = 0; mfi < 4; ++mfi) {
    int col0 = w * 64 + mfi * 16 + (lg << 2);
    f32x4 bv = *(const f32x4*)(bo2 + col0);
#pragma unroll
    for (int nfi = 0; nfi < 2; ++nfi) {
      int row = nfi * 16 + lr;
      U64q ph, pl;
#pragma unroll
      for (int i2 = 0; i2 < 4; ++i2) {
        float x = fmaxf(acc2[mfi][nfi][i2] + bv[i2], 0.f);
        ph.q[i2] = (__bf16)x;
        pl.q[i2] = (__bf16)(x - (float)ph.q[i2]);
      }
      int off = (row * 512 + col0 * 2) ^ ((row & 7) << 4);
      *(unsigned long long*)(h2hi + off) = ph.u;
      *(unsigned long long*)(h2lo + off) = pl.u;
    }
  }
  __syncthreads();

  f32x4 acc3[2] = {};
#pragma unroll
  for (int kk = 0; kk < 8; ++kk) {
    int colp = w * 16 + lr;
    int gb = colp * 512 + kk * 64 + (lg << 4);
    bf16x8 a3h = *(const bf16x8*)(o3h + gb);
    bf16x8 a3l = *(const bf16x8*)(o3l + gb);
#pragma unroll
    for (int nfi = 0; nfi < 2; ++nfi) {
      int row = nfi * 16 + lr;
      int off = (row * 512 + kk * 64 + (lg << 4)) ^ ((row & 7) << 4);
      bf16x8 b3h = *(const bf16x8*)(h2hi + off);
      bf16x8 b3l = *(const bf16x8*)(h2lo + off);
      acc3[nfi] = MFMA16(a3h, b3h, acc3[nfi]);
      acc3[nfi] = MFMA16(a3h, b3l, acc3[nfi]);
      acc3[nfi] = MFMA16(a3l, b3h, acc3[nfi]);
    }
  }
#pragma unroll
  for (int nfi = 0; nfi < 2; ++nfi) {
    int row = nfi * 16 + lr;
    int col0 = w * 16 + (lg << 2);
    f32x4 bv = *(const f32x4*)(bo3 + col0);
    f32x4 iv = *(const f32x4*)(inputs + (r0 + row) * 64 + col0);
    f32x4 o;
#pragma unroll
    for (int i2 = 0; i2 < 4; ++i2) o[i2] = acc3[nfi][i2] + bv[i2] + iv[i2];
    *(f32x4*)(out + (r0 + row) * 64 + col0) = o;
  }
}

// ===========================================================================
extern "C" void kernel_launch(void* const* d_in, const int* in_sizes, int n_in,
                              void* d_out, int out_size, void* d_ws, size_t ws_size,
                              hipStream_t stream) {
  (void)in_sizes; (void)n_in; (void)out_size;
  if (ws_size < (size_t)WS_NEED) return;  // 10 MB

  const float* inputs   = (const float*)d_in[0];
  const float* rel_type = (const float*)d_in[1];
  const float* W1  = (const float*)d_in[4];
  const float* b1  = (const float*)d_in[5];
  const float* W2  = (const float*)d_in[6];
  const float* b2  = (const float*)d_in[7];
  const float* Wo1 = (const float*)d_in[8];
  const float* bo1 = (const float*)d_in[9];
  const float* Wo2 = (const float*)d_in[10];
  const float* bo2 = (const float*)d_in[11];
  const float* Wo3 = (const float*)d_in[12];
  const float* bo3 = (const float*)d_in[13];

  char* ws = (char*)d_ws;
  float* agg = (float*)(ws + WS_AGG);
  float* out = (float*)d_out;

  k0_convert<<<dim3(2240), dim3(256), 0, stream>>>(W1, W2, Wo1, Wo2, Wo3, ws);
  k0b_hr<<<dim3(64), dim3(256), 0, stream>>>(inputs, b1, ws, ws + WS_HR);
  k1_edge<<<dim3(1024), dim3(256), 0, stream>>>(inputs, rel_type, b2, ws, agg);
  k3_node<<<dim3(128), dim3(256), 0, stream>>>(inputs, agg, ws, bo1, bo2, bo3, out);
}

// Round 12
// 254.437 us; speedup vs baseline: 1.4579x; 1.0374x over previous
//
#include <hip/hip_runtime.h>
#include <stdint.h>

// ---------------------------------------------------------------------------
// NRI-style graph block, v12: OCCUPANCY-FIRST edge MLP.
// R1-R11 unified diagnosis: every round ran ~8 waves/CU (2/SIMD) -- reg cap
// (VGPR_Count EXCLUDES AGPR accumulators in the unified file) or LDS cap --
// so all data-path restructures were latency-bound identically.
// v12: LDS = 16KB (h1 half only); weights in FRAGMENT-MAJOR global layout
// (k0) -> coalesced 16B/lane L2 loads, no staging; regs trimmed to ~125
// total => 4 blocks/CU resident = 16 waves/CU (2x everything prior).
//   K0 : weights fp32->bf16, frag-major W1send/W2, inputs->bf16, agg zero
//   K0b: hr[b,r,kap,:] = W1recv @ x_r + b1  (rank-1 receiver part, bf16)
//   K1 : block=(kap,b,16 receivers); per-unit G1->h1(LDS)->G2; atomicAdd agg
//   K3 : node MLP split-bf16 (hi+lo 3-term MFMA) + residual
// ---------------------------------------------------------------------------

typedef __attribute__((ext_vector_type(8))) __bf16 bf16x8;
typedef __attribute__((ext_vector_type(4))) float  f32x4;

#define MFMA16(a, b, c) __builtin_amdgcn_mfma_f32_16x16x32_bf16((a), (b), (c), 0, 0, 0)

union U64q { unsigned long long u; __bf16 q[4]; };

static __device__ __forceinline__ unsigned short bfb(__bf16 x) {
  union { __bf16 b; unsigned short u; } c; c.b = x; return c.u;
}

// ---- ws layout (bytes) ----
#define WS_W1    0          // [4][256][128] bf16  (262144)  (k0b recv half)
#define WS_W2    262144     // [4][64][256] bf16   (131072)  (unused by k1 now)
#define WS_O1H   393216     // [256][128] bf16 hi  (65536)
#define WS_O1L   458752
#define WS_O2H   524288     // [256][256] bf16     (131072)
#define WS_O2L   655360
#define WS_O3H   786432     // [64][256] bf16      (32768)
#define WS_O3L   819200
#define WS_AGG   1048576    // [B*N][64] f32       (1048576) -- atomic target
#define WS_HR    2097152    // [64][64][4][256] bf16 (8388608)
#define WS_IB    10485760   // inputs bf16 [64][64][64] (524288)
#define WS_W1F   11010048   // frag-major W1send [4][16 mt][2 kc][64 lane][8] (131072)
#define WS_W2F   11141120   // frag-major W2 [4][4 ft][8 kw][64 lane][8]     (131072)
#define WS_NEED  11272192   // ~10.75 MB

// ===========================================================================
// K0: weight conversion + frag-major packs + inputs bf16 + agg zero
// 966656 items = 3776 blocks x 256
// ===========================================================================
__global__ __launch_bounds__(256) void k0_convert(
    const float* __restrict__ inputs,
    const float* __restrict__ W1, const float* __restrict__ W2,
    const float* __restrict__ Wo1, const float* __restrict__ Wo2,
    const float* __restrict__ Wo3, char* __restrict__ ws) {
  int i = blockIdx.x * 256 + threadIdx.x;
  if (i < 131072) { ((__bf16*)(ws + WS_W1))[i] = (__bf16)W1[i]; return; }
  i -= 131072;
  if (i < 65536) { ((__bf16*)(ws + WS_W2))[i] = (__bf16)W2[i]; return; }
  i -= 65536;
  if (i < 32768) { float v = Wo1[i]; __bf16 h = (__bf16)v;
    ((__bf16*)(ws + WS_O1H))[i] = h; ((__bf16*)(ws + WS_O1L))[i] = (__bf16)(v - (float)h); return; }
  i -= 32768;
  if (i < 65536) { float v = Wo2[i]; __bf16 h = (__bf16)v;
    ((__bf16*)(ws + WS_O2H))[i] = h; ((__bf16*)(ws + WS_O2L))[i] = (__bf16)(v - (float)h); return; }
  i -= 65536;
  if (i < 16384) { float v = Wo3[i]; __bf16 h = (__bf16)v;
    ((__bf16*)(ws + WS_O3H))[i] = h; ((__bf16*)(ws + WS_O3L))[i] = (__bf16)(v - (float)h); return; }
  i -= 16384;
  if (i < 262144) { ((float*)(ws + WS_AGG))[i] = 0.f; return; }
  i -= 262144;
  if (i < 262144) { ((__bf16*)(ws + WS_IB))[i] = (__bf16)inputs[i]; return; }
  i -= 262144;
  if (i < 65536) {   // W1F: lane l holds col=mt*16+(l&15), k=kc*32+(l>>4)*8+j (send)
    int j = i & 7, lane = (i >> 3) & 63, kc = (i >> 9) & 1, mt = (i >> 10) & 15, kap = i >> 14;
    int col = mt * 16 + (lane & 15);
    int k = 64 + kc * 32 + ((lane >> 4) << 3) + j;
    ((__bf16*)(ws + WS_W1F))[i] = (__bf16)W1[(kap * 256 + col) * 128 + k];
    return;
  }
  i -= 65536;
  if (i < 65536) {   // W2F: lane l holds feat=ft*16+(l&15), k=kw*32+(l>>4)*8+j
    int j = i & 7, lane = (i >> 3) & 63, kw = (i >> 9) & 7, ft = (i >> 12) & 3, kap = i >> 14;
    int feat = ft * 16 + (lane & 15);
    int k = kw * 32 + ((lane >> 4) << 3) + j;
    ((__bf16*)(ws + WS_W2F))[i] = (__bf16)W2[(kap * 64 + feat) * 256 + k];
    return;
  }
}

// ===========================================================================
// K0b: hr[b][r][kap][col] = W1recv[kap][col][:]@inputs[b,r,:] + b1[kap][col]
// ===========================================================================
__global__ __launch_bounds__(256) void k0b_hr(
    const float* __restrict__ inputs, const float* __restrict__ b1g,
    const char* __restrict__ wsr, char* __restrict__ hrout) {
  const int b = blockIdx.x;
  const int tid = threadIdx.x, l = tid & 63, w = tid >> 6;  // w = kap
  const int lg = l >> 4, lr = l & 15;

  bf16x8 bfr[4][2];
#pragma unroll
  for (int nt = 0; nt < 4; ++nt)
#pragma unroll
    for (int kc = 0; kc < 2; ++kc) {
      const float* p = inputs + ((size_t)b * 64 + nt * 16 + lr) * 64 + kc * 32 + lg * 8;
      f32x4 v0 = *(const f32x4*)p, v1 = *(const f32x4*)(p + 4);
      bf16x8 t;
#pragma unroll
      for (int j = 0; j < 4; ++j) { t[j] = (__bf16)v0[j]; t[4 + j] = (__bf16)v1[j]; }
      bfr[nt][kc] = t;
    }

  const char* w1 = wsr + WS_W1;
#pragma unroll 1
  for (int cb = 0; cb < 4; ++cb) {
    f32x4 acc[4][4] = {};
#pragma unroll
    for (int kc = 0; kc < 2; ++kc)
#pragma unroll
      for (int mt = 0; mt < 4; ++mt) {
        int col = w * 256 + cb * 64 + mt * 16 + lr;
        bf16x8 af = *(const bf16x8*)(w1 + (col << 8) + kc * 64 + (lg << 4));
#pragma unroll
        for (int nt = 0; nt < 4; ++nt)
          acc[mt][nt] = MFMA16(af, bfr[nt][kc], acc[mt][nt]);
      }
#pragma unroll
    for (int mt = 0; mt < 4; ++mt) {
      int col0 = cb * 64 + mt * 16 + (lg << 2);
      f32x4 bv = *(const f32x4*)(b1g + w * 256 + col0);
#pragma unroll
      for (int nt = 0; nt < 4; ++nt) {
        int r = nt * 16 + lr;
        U64q pk;
#pragma unroll
        for (int i2 = 0; i2 < 4; ++i2) pk.q[i2] = (__bf16)(acc[mt][nt][i2] + bv[i2]);
        *(unsigned long long*)(hrout + ((((size_t)b * 64 + r) * 4 + w) * 256 + col0) * 2) = pk.u;
      }
    }
  }
}

// ===========================================================================
// K1 v12: block = (kap, b, 16 receivers). 256 thr / 4 waves. LDS = 16KB only.
// Per unit: 2 halves x { G1 (frag-major W1 from L2, bs from ib) -> h1S;
// barrier; G2 (frag-major W2 from L2, b2f from h1S); barrier } -> gate ->
// shuffle-reduce -> atomicAdd agg. Peak regs ~125 -> 4 waves/SIMD; 4 blk/CU.
// ===========================================================================
__global__ __launch_bounds__(256) void k1_edge(
    const __bf16* __restrict__ ib, const float* __restrict__ rel_type,
    const float* __restrict__ b2g, const char* __restrict__ wsr,
    float* __restrict__ agg) {
  __shared__ char h1S[16384];    // [64 slots][256B] (one col-half), ^((slot&7)<<4)

  const int tid = threadIdx.x;
  const int bid = blockIdx.x;
  const int kap = bid >> 8;             // grid = 4 * 64 * 4 = 1024
  const int rem = bid & 255;
  const int b   = rem >> 2;
  const int n0  = (rem & 3) << 4;
  const int l = tid & 63, w = tid >> 6;
  const int lg = l >> 4, lr = l & 15;
  const int wm = w >> 1, wn = w & 1;    // G2 grid: 2m (feat half) x 2n (slot half)

  const char* w1f = wsr + WS_W1F;
  const char* w2f = wsr + WS_W2F;
  const char* hrp = wsr + WS_HR;
  const __bf16* ibB = ib + (size_t)b * 4096;

  // b2 quads (constant per block)
  f32x4 bv2[2];
#pragma unroll
  for (int mf2 = 0; mf2 < 2; ++mf2)
    bv2[mf2] = *(const f32x4*)(b2g + kap * 64 + wm * 32 + mf2 * 16 + (lg << 2));

#pragma unroll 1
  for (int u = 0; u < 16; ++u) {
    const int n = n0 + u;

    // rel_type gates (pad slot -> 0)
    float rt[2];
#pragma unroll
    for (int nf2 = 0; nf2 < 2; ++nf2) {
      int slot = wn * 32 + nf2 * 16 + lr;
      rt[nf2] = (slot < 63) ? rel_type[((size_t)b * 4032 + n * 63 + slot) * 4 + kap] : 0.f;
    }

    f32x4 acc2[2][2] = {};             // [mf2][nf2], accum across halves (16 acc regs)

#pragma unroll 1
    for (int mh = 0; mh < 2; ++mh) {
      // hv prefetch for this half (consumed after G1 MFMAs)
      unsigned long long hvp[2];
      {
        const char* hb = hrp + (((size_t)(b * 64 + n)) * 4 + kap) * 512;
#pragma unroll
        for (int mt = 0; mt < 2; ++mt) {
          int col0 = mh * 128 + w * 32 + mt * 16 + (lg << 2);
          hvp[mt] = *(const unsigned long long*)(hb + col0 * 2);
        }
      }

      // ===== G1 half: wave w covers 32 cols (2 tiles); acc1 = 32 acc regs =====
      f32x4 acc1[2][4] = {};
#pragma unroll
      for (int kc = 0; kc < 2; ++kc) {
        // bs: sender B-frags from pre-converted bf16 inputs (single 16B loads)
        bf16x8 bs[4];
#pragma unroll
        for (int nf = 0; nf < 4; ++nf) {
          int slot = nf * 16 + lr;
          int j = slot < 63 ? slot : 62;   // pad dups j=62 (rt gate = 0)
          int s = j + (j >= n ? 1 : 0);
          bs[nf] = *(const bf16x8*)(ibB + s * 64 + kc * 32 + lg * 8);
        }
        // W1 A-frags: frag-major, lane-contiguous 1KB (coalesced L2)
        bf16x8 W1a[2];
#pragma unroll
        for (int mt = 0; mt < 2; ++mt) {
          int mtg = mh * 8 + w * 2 + mt;
          W1a[mt] = *(const bf16x8*)(w1f + (((kap * 16 + mtg) * 2 + kc) * 512 + l * 8) * 2);
        }
#pragma unroll
        for (int mt = 0; mt < 2; ++mt)
#pragma unroll
          for (int nf = 0; nf < 4; ++nf)
            acc1[mt][nf] = MFMA16(W1a[mt], bs[nf], acc1[mt][nf]);
      }

      // epilogue: + hv (recv part incl b1), relu, bf16 -> h1S
#pragma unroll
      for (int mt = 0; mt < 2; ++mt) {
        int lc = w * 32 + mt * 16 + (lg << 2);       // col within half
        U64q hv; hv.u = hvp[mt];
#pragma unroll
        for (int nf = 0; nf < 4; ++nf) {
          int slot = nf * 16 + lr;
          U64q pk;
#pragma unroll
          for (int i2 = 0; i2 < 4; ++i2)
            pk.q[i2] = (__bf16)fmaxf(acc1[mt][nf][i2] + (float)hv.q[i2], 0.f);
          int off = (slot * 256 + lc * 2) ^ ((slot & 7) << 4);
          *(unsigned long long*)(h1S + off) = pk.u;
        }
      }
      __syncthreads();   // h1 half ready

      // ===== G2 partial: K window [mh*128,+128) =====
#pragma unroll
      for (int kc2 = 0; kc2 < 4; ++kc2) {
        bf16x8 a2[2], b2f[2];
#pragma unroll
        for (int mf2 = 0; mf2 < 2; ++mf2) {
          int ft = wm * 2 + mf2;
          int kw = mh * 4 + kc2;
          a2[mf2] = *(const bf16x8*)(w2f + (((kap * 4 + ft) * 8 + kw) * 512 + l * 8) * 2);
        }
#pragma unroll
        for (int nf2 = 0; nf2 < 2; ++nf2) {
          int slot = wn * 32 + nf2 * 16 + lr;
          int kb = (kc2 * 32 + lg * 8) * 2;
          b2f[nf2] = *(const bf16x8*)(h1S + ((slot * 256 + kb) ^ ((slot & 7) << 4)));
        }
#pragma unroll
        for (int mf2 = 0; mf2 < 2; ++mf2)
#pragma unroll
          for (int nf2 = 0; nf2 < 2; ++nf2)
            acc2[mf2][nf2] = MFMA16(a2[mf2], b2f[nf2], acc2[mf2][nf2]);
      }
      __syncthreads();   // h1 consumed before next half / next unit overwrites
    }

    // ---- gate + reduce over slots -> atomicAdd agg[b,n,:] ----
    float s[2][4];
#pragma unroll
    for (int mf2 = 0; mf2 < 2; ++mf2)
#pragma unroll
      for (int i2 = 0; i2 < 4; ++i2) {
        float v0 = fmaxf(acc2[mf2][0][i2] + bv2[mf2][i2], 0.f) * rt[0];
        float v1 = fmaxf(acc2[mf2][1][i2] + bv2[mf2][i2], 0.f) * rt[1];
        s[mf2][i2] = v0 + v1;
      }
#pragma unroll
    for (int mask = 1; mask < 16; mask <<= 1)
#pragma unroll
      for (int mf2 = 0; mf2 < 2; ++mf2)
#pragma unroll
        for (int i2 = 0; i2 < 4; ++i2)
          s[mf2][i2] += __shfl_xor(s[mf2][i2], mask);

    if (lr == 0) {
      float* dst = agg + ((size_t)b * 64 + n) * 64;
#pragma unroll
      for (int mf2 = 0; mf2 < 2; ++mf2) {
        int f0 = wm * 32 + mf2 * 16 + (lg << 2);
#pragma unroll
        for (int i2 = 0; i2 < 4; ++i2)
          atomicAdd(dst + f0 + i2, s[mf2][i2]);
      }
    }
  }
}

// ===========================================================================
// K3: node MLP with split-bf16 (hi+lo) 3-term MFMA + residual
// ===========================================================================
__global__ __launch_bounds__(256) void k3_node(
    const float* __restrict__ inputs, const float* __restrict__ agg,
    const char* __restrict__ wsr,
    const float* __restrict__ bo1, const float* __restrict__ bo2,
    const float* __restrict__ bo3, float* __restrict__ out) {
  __shared__ char sm[65536];
  char* augHi = sm;                  // [32][128] bf16 swz
  char* augLo = sm + 8192;
  char* h1hi  = sm + 16384;          // [32][256] bf16 swz
  char* h1lo  = sm + 32768;
  char* h2hi  = sm;                  // reuse aug region after GEMM1
  char* h2lo  = sm + 49152;

  const char* o1h = wsr + WS_O1H;
  const char* o1l = wsr + WS_O1L;
  const char* o2h = wsr + WS_O2H;
  const char* o2l = wsr + WS_O2L;
  const char* o3h = wsr + WS_O3H;
  const char* o3l = wsr + WS_O3L;

  const int tid = threadIdx.x;
  const int l = tid & 63;
  const int w = tid >> 6;
  const int lg = l >> 4, lr = l & 15;
  const int r0 = blockIdx.x * 32;

  for (int it = 0; it < 8; ++it) {
    int u = tid + it * 256;
    int row = u >> 6, up = u & 63;
    int col = up * 2;
    const float* src = (col < 64) ? (inputs + (r0 + row) * 64 + col)
                                  : (agg + (r0 + row) * 64 + (col - 64));
    float2 v = *(const float2*)src;
    __bf16 h0 = (__bf16)v.x, h1v = (__bf16)v.y;
    __bf16 l0 = (__bf16)(v.x - (float)h0), l1 = (__bf16)(v.y - (float)h1v);
    int off = (row * 256 + col * 2) ^ ((row & 7) << 4);
    ushort2 ph; ph.x = bfb(h0); ph.y = bfb(h1v);
    ushort2 pl; pl.x = bfb(l0); pl.y = bfb(l1);
    *(ushort2*)(augHi + off) = ph;
    *(ushort2*)(augLo + off) = pl;
  }
  __syncthreads();

  f32x4 acc[4][2] = {};
#pragma unroll
  for (int kk = 0; kk < 4; ++kk) {
    bf16x8 ah[4], al[4], bh[2], bl[2];
#pragma unroll
    for (int mfi = 0; mfi < 4; ++mfi) {
      int colp = w * 64 + mfi * 16 + lr;
      int gb = colp * 256 + kk * 64 + (lg << 4);
      ah[mfi] = *(const bf16x8*)(o1h + gb);
      al[mfi] = *(const bf16x8*)(o1l + gb);
    }
#pragma unroll
    for (int nfi = 0; nfi < 2; ++nfi) {
      int row = nfi * 16 + lr;
      int off = (row * 256 + kk * 64 + (lg << 4)) ^ ((row & 7) << 4);
      bh[nfi] = *(const bf16x8*)(augHi + off);
      bl[nfi] = *(const bf16x8*)(augLo + off);
    }
#pragma unroll
    for (int mfi = 0; mfi < 4; ++mfi)
#pragma unroll
      for (int nfi = 0; nfi < 2; ++nfi) {
        acc[mfi][nfi] = MFMA16(ah[mfi], bh[nfi], acc[mfi][nfi]);
        acc[mfi][nfi] = MFMA16(ah[mfi], bl[nfi], acc[mfi][nfi]);
        acc[mfi][nfi] = MFMA16(al[mfi], bh[nfi], acc[mfi][nfi]);
      }
  }
#pragma unroll
  for (int mfi = 0; mfi < 4; ++mfi) {
    int col0 = w * 64 + mfi * 16 + (lg << 2);
    f32x4 bv = *(const f32x4*)(bo1 + col0);
#pragma unroll
    for (int nfi = 0; nfi < 2; ++nfi) {
      int row = nfi * 16 + lr;
      U64q ph, pl;
#pragma unroll
      for (int i2 = 0; i2 < 4; ++i2) {
        float x = fmaxf(acc[mfi][nfi][i2] + bv[i2], 0.f);
        ph.q[i2] = (__bf16)x;
        pl.q[i2] = (__bf16)(x - (float)ph.q[i2]);
      }
      int off = (row * 512 + col0 * 2) ^ ((row & 7) << 4);
      *(unsigned long long*)(h1hi + off) = ph.u;
      *(unsigned long long*)(h1lo + off) = pl.u;
    }
  }
  __syncthreads();

  f32x4 acc2[4][2] = {};
#pragma unroll
  for (int kk = 0; kk < 8; ++kk) {
    bf16x8 ah[4], al[4], bh[2], bl[2];
#pragma unroll
    for (int mfi = 0; mfi < 4; ++mfi) {
      int colp = w * 64 + mfi * 16 + lr;
      int gb = colp * 512 + kk * 64 + (lg << 4);
      ah[mfi] = *(const bf16x8*)(o2h + gb);
      al[mfi] = *(const bf16x8*)(o2l + gb);
    }
#pragma unroll
    for (int nfi = 0; nfi < 2; ++nfi) {
      int row = nfi * 16 + lr;
      int off = (row * 512 + kk * 64 + (lg << 4)) ^ ((row & 7) << 4);
      bh[nfi] = *(const bf16x8*)(h1hi + off);
      bl[nfi] = *(const bf16x8*)(h1lo + off);
    }
#pragma unroll
    for (int mfi = 0; mfi < 4; ++mfi)
#pragma unroll
      for (int nfi = 0; nfi < 2; ++nfi) {
        acc2[mfi][nfi] = MFMA16(ah[mfi], bh[nfi], acc2[mfi][nfi]);
        acc2[mfi][nfi] = MFMA16(ah[mfi], bl[nfi], acc2[mfi][nfi]);
        acc2[mfi][nfi] = MFMA16(al[mfi], bh[nfi], acc2[mfi][nfi]);
      }
  }
#pragma unroll
  for (int mfi = 0; mfi < 4; ++mfi) {
    int col0 = w * 64 + mfi * 16 + (lg << 2);
    f32x4 bv = *(const f32x4*)(bo2 + col0);
#pragma unroll
    for (int nfi = 0; nfi < 2; ++nfi) {
      int row = nfi * 16 + lr;
      U64q ph, pl;
#pragma unroll
      for (int i2 = 0; i2 < 4; ++i2) {
        float x = fmaxf(acc2[mfi][nfi][i2] + bv[i2], 0.f);
        ph.q[i2] = (__bf16)x;
        pl.q[i2] = (__bf16)(x - (float)ph.q[i2]);
      }
      int off = (row * 512 + col0 * 2) ^ ((row & 7) << 4);
      *(unsigned long long*)(h2hi + off) = ph.u;
      *(unsigned long long*)(h2lo + off) = pl.u;
    }
  }
  __syncthreads();

  f32x4 acc3[2] = {};
#pragma unroll
  for (int kk = 0; kk < 8; ++kk) {
    int colp = w * 16 + lr;
    int gb = colp * 512 + kk * 64 + (lg << 4);
    bf16x8 a3h = *(const bf16x8*)(o3h + gb);
    bf16x8 a3l = *(const bf16x8*)(o3l + gb);
#pragma unroll
    for (int nfi = 0; nfi < 2; ++nfi) {
      int row = nfi * 16 + lr;
      int off = (row * 512 + kk * 64 + (lg << 4)) ^ ((row & 7) << 4);
      bf16x8 b3h = *(const bf16x8*)(h2hi + off);
      bf16x8 b3l = *(const bf16x8*)(h2lo + off);
      acc3[nfi] = MFMA16(a3h, b3h, acc3[nfi]);
      acc3[nfi] = MFMA16(a3h, b3l, acc3[nfi]);
      acc3[nfi] = MFMA16(a3l, b3h, acc3[nfi]);
    }
  }
#pragma unroll
  for (int nfi = 0; nfi < 2; ++nfi) {
    int row = nfi * 16 + lr;
    int col0 = w * 16 + (lg << 2);
    f32x4 bv = *(const f32x4*)(bo3 + col0);
    f32x4 iv = *(const f32x4*)(inputs + (r0 + row) * 64 + col0);
    f32x4 o;
#pragma unroll
    for (int i2 = 0; i2 < 4; ++i2) o[i2] = acc3[nfi][i2] + bv[i2] + iv[i2];
    *(f32x4*)(out + (r0 + row) * 64 + col0) = o;
  }
}

// ===========================================================================
extern "C" void kernel_launch(void* const* d_in, const int* in_sizes, int n_in,
                              void* d_out, int out_size, void* d_ws, size_t ws_size,
                              hipStream_t stream) {
  (void)in_sizes; (void)n_in; (void)out_size;
  if (ws_size < (size_t)WS_NEED) return;  // ~10.75 MB

  const float* inputs   = (const float*)d_in[0];
  const float* rel_type = (const float*)d_in[1];
  const float* W1  = (const float*)d_in[4];
  const float* b1  = (const float*)d_in[5];
  const float* W2  = (const float*)d_in[6];
  const float* b2  = (const float*)d_in[7];
  const float* Wo1 = (const float*)d_in[8];
  const float* bo1 = (const float*)d_in[9];
  const float* Wo2 = (const float*)d_in[10];
  const float* bo2 = (const float*)d_in[11];
  const float* Wo3 = (const float*)d_in[12];
  const float* bo3 = (const float*)d_in[13];

  char* ws = (char*)d_ws;
  float* agg = (float*)(ws + WS_AGG);
  float* out = (float*)d_out;

  k0_convert<<<dim3(3776), dim3(256), 0, stream>>>(inputs, W1, W2, Wo1, Wo2, Wo3, ws);
  k0b_hr<<<dim3(64), dim3(256), 0, stream>>>(inputs, b1, ws, ws + WS_HR);
  k1_edge<<<dim3(1024), dim3(256), 0, stream>>>((const __bf16*)(ws + WS_IB),
                                                rel_type, b2, ws, agg);
  k3_node<<<dim3(128), dim3(256), 0, stream>>>(inputs, agg, ws, bo1, bo2, bo3, out);
}

// Round 13
// 128.402 us; speedup vs baseline: 2.8890x; 1.9816x over previous
//
#include <hip/hip_runtime.h>
#include <stdint.h>

// ---------------------------------------------------------------------------
// NRI-style graph block, v13: RANK-1 FACTORED edge MLP (GEMM1 eliminated).
// h1[e] = relu(W1r@x_r + W1s@x_s + b1) = relu(Q[r] + P[s]) with per-node
// P = W1s@x (kPQ, 1.1 GF), Q = W1r@x + b1. k1 only runs GEMM2 (34 GF):
// per (kap,b,receiver): stream P (32KB coalesced, L2-resident via XCD-affine
// blockIdx: bid%8 == b%8) + Q broadcast -> VALU add/relu -> h1S(32KB LDS)
// -> G2 (frag-major W2 from L2) -> gate -> shuffle-reduce -> atomicAdd agg.
//   K0 : weight converts + frag-major W2 + agg zero
//   kPQ: P/Q per (b, node, kap) via MFMA (k0b structure, verified R9-12)
//   K1 : edge MLP, GEMM2-only
//   K3 : node MLP split-bf16 (hi+lo 3-term MFMA) + residual
// ---------------------------------------------------------------------------

typedef __attribute__((ext_vector_type(8))) __bf16 bf16x8;
typedef __attribute__((ext_vector_type(4))) float  f32x4;

#define MFMA16(a, b, c) __builtin_amdgcn_mfma_f32_16x16x32_bf16((a), (b), (c), 0, 0, 0)

union U64q { unsigned long long u; __bf16 q[4]; };

static __device__ __forceinline__ unsigned short bfb(__bf16 x) {
  union { __bf16 b; unsigned short u; } c; c.b = x; return c.u;
}

// ---- ws layout (bytes) ----
#define WS_W1    0          // [4][256][128] bf16 (262144)  (kPQ source)
#define WS_O1H   262144     // [256][128] bf16 hi (65536)
#define WS_O1L   327680
#define WS_O2H   393216     // [256][256] bf16 (131072)
#define WS_O2L   524288
#define WS_O3H   655360     // [64][256] bf16 (32768)
#define WS_O3L   688128
#define WS_AGG   720896     // [B*N][64] f32 (1048576) -- atomic target
#define WS_W2F   1769472    // frag-major W2 [4][4 ft][8 kw][64 lane][8] (131072)
#define WS_P     1900544    // [b][kap][s][256] bf16 (8388608)
#define WS_Q     10289152   // [b][kap][n][256] bf16 (8388608)
#define WS_NEED  18677760   // ~17.8 MB

// ===========================================================================
// K0: weight conversion + frag-major W2 + agg zero. 573440 items, 2240 blocks.
// ===========================================================================
__global__ __launch_bounds__(256) void k0_convert(
    const float* __restrict__ W1, const float* __restrict__ W2,
    const float* __restrict__ Wo1, const float* __restrict__ Wo2,
    const float* __restrict__ Wo3, char* __restrict__ ws) {
  int i = blockIdx.x * 256 + threadIdx.x;
  if (i < 131072) { ((__bf16*)(ws + WS_W1))[i] = (__bf16)W1[i]; return; }
  i -= 131072;
  if (i < 32768) { float v = Wo1[i]; __bf16 h = (__bf16)v;
    ((__bf16*)(ws + WS_O1H))[i] = h; ((__bf16*)(ws + WS_O1L))[i] = (__bf16)(v - (float)h); return; }
  i -= 32768;
  if (i < 65536) { float v = Wo2[i]; __bf16 h = (__bf16)v;
    ((__bf16*)(ws + WS_O2H))[i] = h; ((__bf16*)(ws + WS_O2L))[i] = (__bf16)(v - (float)h); return; }
  i -= 65536;
  if (i < 16384) { float v = Wo3[i]; __bf16 h = (__bf16)v;
    ((__bf16*)(ws + WS_O3H))[i] = h; ((__bf16*)(ws + WS_O3L))[i] = (__bf16)(v - (float)h); return; }
  i -= 16384;
  if (i < 262144) { ((float*)(ws + WS_AGG))[i] = 0.f; return; }
  i -= 262144;
  if (i < 65536) {   // W2F: lane l holds feat=ft*16+(l&15), k=kw*32+(l>>4)*8+j
    int j = i & 7, lane = (i >> 3) & 63, kw = (i >> 9) & 7, ft = (i >> 12) & 3, kap = i >> 14;
    int feat = ft * 16 + (lane & 15);
    int k = kw * 32 + ((lane >> 4) << 3) + j;
    ((__bf16*)(ws + WS_W2F))[i] = (__bf16)W2[(kap * 64 + feat) * 256 + k];
    return;
  }
}

// ===========================================================================
// kPQ: P[b][kap][s][:] = W1send[kap]@x_s ; Q[b][kap][n][:] = W1recv[kap]@x_n+b1
// grid = 64 b x 2 (isP). 256 thr; wave w = kap. (k0b structure, verified.)
// ===========================================================================
__global__ __launch_bounds__(256) void kPQ(
    const float* __restrict__ inputs, const float* __restrict__ b1g,
    const char* __restrict__ wsr, char* __restrict__ ws) {
  const int b = blockIdx.x >> 1;
  const int isP = blockIdx.x & 1;
  const int tid = threadIdx.x, l = tid & 63, w = tid >> 6;  // w = kap
  const int lg = l >> 4, lr = l & 15;

  bf16x8 bfr[4][2];
#pragma unroll
  for (int nt = 0; nt < 4; ++nt)
#pragma unroll
    for (int kc = 0; kc < 2; ++kc) {
      const float* p = inputs + ((size_t)b * 64 + nt * 16 + lr) * 64 + kc * 32 + lg * 8;
      f32x4 v0 = *(const f32x4*)p, v1 = *(const f32x4*)(p + 4);
      bf16x8 t;
#pragma unroll
      for (int j = 0; j < 4; ++j) { t[j] = (__bf16)v0[j]; t[4 + j] = (__bf16)v1[j]; }
      bfr[nt][kc] = t;
    }

  const char* w1 = wsr + WS_W1 + (isP ? 128 : 0);   // send half at +128B
  char* outb = ws + (isP ? WS_P : WS_Q);
#pragma unroll 1
  for (int cb = 0; cb < 4; ++cb) {
    f32x4 acc[4][4] = {};
#pragma unroll
    for (int kc = 0; kc < 2; ++kc)
#pragma unroll
      for (int mt = 0; mt < 4; ++mt) {
        int col = w * 256 + cb * 64 + mt * 16 + lr;      // global W1 row
        bf16x8 af = *(const bf16x8*)(w1 + (col << 8) + kc * 64 + (lg << 4));
#pragma unroll
        for (int nt = 0; nt < 4; ++nt)
          acc[mt][nt] = MFMA16(af, bfr[nt][kc], acc[mt][nt]);
      }
#pragma unroll
    for (int mt = 0; mt < 4; ++mt) {
      int col0 = cb * 64 + mt * 16 + (lg << 2);
      f32x4 bv;
      if (isP) { bv[0] = bv[1] = bv[2] = bv[3] = 0.f; }
      else      bv = *(const f32x4*)(b1g + w * 256 + col0);
#pragma unroll
      for (int nt = 0; nt < 4; ++nt) {
        int r = nt * 16 + lr;
        U64q pk;
#pragma unroll
        for (int i2 = 0; i2 < 4; ++i2) pk.q[i2] = (__bf16)(acc[mt][nt][i2] + bv[i2]);
        *(unsigned long long*)(outb + ((((size_t)b * 4 + w) * 64 + r) * 256 + col0) * 2) = pk.u;
      }
    }
  }
}

// ===========================================================================
// K1 v13: block = (kap, b, 16 receivers), XCD-affine (bid%8 == b%8).
// Per unit n: h1S[s][c] = relu(P[s][c] + Q[n][c]) (streamed, coalesced);
// barrier; G2 (64 feats x 64 slots x K=256, frag-major W2 from L2); barrier;
// gate by rel_type (self-slot 0); shuffle-reduce; atomicAdd agg[b,n,:].
// LDS 32KB; ~2 barriers/unit; zero MFMA for layer 1.
// ===========================================================================
__global__ __launch_bounds__(256) void k1_edge(
    const float* __restrict__ rel_type, const float* __restrict__ b2g,
    const char* __restrict__ wsr, float* __restrict__ agg) {
  __shared__ char h1S[32768];    // [64 s][512B], byte ^= ((s&7)<<4)

  const int tid = threadIdx.x;
  const int bid = blockIdx.x;
  // decode XCD-affine mapping: bid = ((kap*8 + b_hi)*4 + g)*8 + b_lo
  const int b_lo = bid & 7;
  int t = bid >> 3;
  const int g = t & 3; t >>= 2;
  const int b_hi = t & 7;
  const int kap = t >> 3;
  const int b = b_hi * 8 + b_lo;
  const int n0 = g * 16;

  const int l = tid & 63, w = tid >> 6;
  const int lg = l >> 4, lr = l & 15;
  const int wm = w >> 1, wn = w & 1;    // G2 grid: 2m (feat half) x 2n (slot half)

  const char* w2f = wsr + WS_W2F;
  const char* Pb  = wsr + WS_P + ((size_t)(b * 4 + kap)) * 32768;  // [64 s][512B]
  const char* Qb  = wsr + WS_Q + ((size_t)(b * 4 + kap)) * 32768;

  f32x4 bv2[2];
#pragma unroll
  for (int mf2 = 0; mf2 < 2; ++mf2)
    bv2[mf2] = *(const f32x4*)(b2g + kap * 64 + wm * 32 + mf2 * 16 + (lg << 2));

#pragma unroll 1
  for (int u = 0; u < 16; ++u) {
    const int n = n0 + u;
    const char* Qn = Qb + n * 512;

    // rel_type gates (self-slot -> 0); sender s -> edge n*63 + (s - (s>n))
    float rt[2];
#pragma unroll
    for (int nf2 = 0; nf2 < 2; ++nf2) {
      int s = wn * 32 + nf2 * 16 + lr;
      if (s == n) rt[nf2] = 0.f;
      else {
        int e = n * 63 + (s > n ? s - 1 : s);
        rt[nf2] = rel_type[(((size_t)b * 4032) + e) * 4 + kap];
      }
    }

    // ---- h1 build: h1[s][c] = relu(P[s][c] + Q[n][c]), coalesced stream ----
#pragma unroll
    for (int it = 0; it < 8; ++it) {
      int uu = tid + it * 256;          // 0..2047 ; s = uu>>5, c0 = (uu&31)*8
      int s = uu >> 5, c0 = (uu & 31) * 8;
      bf16x8 pv = *(const bf16x8*)(Pb + s * 512 + c0 * 2);
      bf16x8 qv = *(const bf16x8*)(Qn + c0 * 2);
      bf16x8 hv;
#pragma unroll
      for (int j = 0; j < 8; ++j)
        hv[j] = (__bf16)fmaxf((float)pv[j] + (float)qv[j], 0.f);
      *(bf16x8*)(h1S + ((s * 512 + c0 * 2) ^ ((s & 7) << 4))) = hv;
    }
    __syncthreads();   // h1 ready

    // ---- G2: h2 = W2[kap] @ h1^T (M=64 feats, N=64 slots, K=256) ----
    f32x4 acc2[2][2] = {};
#pragma unroll
    for (int kc2 = 0; kc2 < 8; ++kc2) {
      bf16x8 a2[2], b2f[2];
#pragma unroll
      for (int mf2 = 0; mf2 < 2; ++mf2) {
        int ft = wm * 2 + mf2;
        a2[mf2] = *(const bf16x8*)(w2f + (((kap * 4 + ft) * 8 + kc2) * 512 + l * 8) * 2);
      }
#pragma unroll
      for (int nf2 = 0; nf2 < 2; ++nf2) {
        int s = wn * 32 + nf2 * 16 + lr;
        b2f[nf2] = *(const bf16x8*)(h1S + ((s * 512 + (kc2 * 32 + lg * 8) * 2) ^ ((s & 7) << 4)));
      }
#pragma unroll
      for (int mf2 = 0; mf2 < 2; ++mf2)
#pragma unroll
        for (int nf2 = 0; nf2 < 2; ++nf2)
          acc2[mf2][nf2] = MFMA16(a2[mf2], b2f[nf2], acc2[mf2][nf2]);
    }
    __syncthreads();   // h1 consumed before next unit overwrites

    // ---- gate + reduce over slots -> atomicAdd agg[b,n,:] ----
    float s[2][4];
#pragma unroll
    for (int mf2 = 0; mf2 < 2; ++mf2)
#pragma unroll
      for (int i2 = 0; i2 < 4; ++i2) {
        float v0 = fmaxf(acc2[mf2][0][i2] + bv2[mf2][i2], 0.f) * rt[0];
        float v1 = fmaxf(acc2[mf2][1][i2] + bv2[mf2][i2], 0.f) * rt[1];
        s[mf2][i2] = v0 + v1;
      }
#pragma unroll
    for (int mask = 1; mask < 16; mask <<= 1)
#pragma unroll
      for (int mf2 = 0; mf2 < 2; ++mf2)
#pragma unroll
        for (int i2 = 0; i2 < 4; ++i2)
          s[mf2][i2] += __shfl_xor(s[mf2][i2], mask);

    if (lr == 0) {
      float* dst = agg + ((size_t)b * 64 + n) * 64;
#pragma unroll
      for (int mf2 = 0; mf2 < 2; ++mf2) {
        int f0 = wm * 32 + mf2 * 16 + (lg << 2);
#pragma unroll
        for (int i2 = 0; i2 < 4; ++i2)
          atomicAdd(dst + f0 + i2, s[mf2][i2]);
      }
    }
  }
}

// ===========================================================================
// K3: node MLP with split-bf16 (hi+lo) 3-term MFMA + residual
// ===========================================================================
__global__ __launch_bounds__(256) void k3_node(
    const float* __restrict__ inputs, const float* __restrict__ agg,
    const char* __restrict__ wsr,
    const float* __restrict__ bo1, const float* __restrict__ bo2,
    const float* __restrict__ bo3, float* __restrict__ out) {
  __shared__ char sm[65536];
  char* augHi = sm;                  // [32][128] bf16 swz
  char* augLo = sm + 8192;
  char* h1hi  = sm + 16384;          // [32][256] bf16 swz
  char* h1lo  = sm + 32768;
  char* h2hi  = sm;                  // reuse aug region after GEMM1
  char* h2lo  = sm + 49152;

  const char* o1h = wsr + WS_O1H;
  const char* o1l = wsr + WS_O1L;
  const char* o2h = wsr + WS_O2H;
  const char* o2l = wsr + WS_O2L;
  const char* o3h = wsr + WS_O3H;
  const char* o3l = wsr + WS_O3L;

  const int tid = threadIdx.x;
  const int l = tid & 63;
  const int w = tid >> 6;
  const int lg = l >> 4, lr = l & 15;
  const int r0 = blockIdx.x * 32;

  for (int it = 0; it < 8; ++it) {
    int u = tid + it * 256;
    int row = u >> 6, up = u & 63;
    int col = up * 2;
    const float* src = (col < 64) ? (inputs + (r0 + row) * 64 + col)
                                  : (agg + (r0 + row) * 64 + (col - 64));
    float2 v = *(const float2*)src;
    __bf16 h0 = (__bf16)v.x, h1v = (__bf16)v.y;
    __bf16 l0 = (__bf16)(v.x - (float)h0), l1 = (__bf16)(v.y - (float)h1v);
    int off = (row * 256 + col * 2) ^ ((row & 7) << 4);
    ushort2 ph; ph.x = bfb(h0); ph.y = bfb(h1v);
    ushort2 pl; pl.x = bfb(l0); pl.y = bfb(l1);
    *(ushort2*)(augHi + off) = ph;
    *(ushort2*)(augLo + off) = pl;
  }
  __syncthreads();

  f32x4 acc[4][2] = {};
#pragma unroll
  for (int kk = 0; kk < 4; ++kk) {
    bf16x8 ah[4], al[4], bh[2], bl[2];
#pragma unroll
    for (int mfi = 0; mfi < 4; ++mfi) {
      int colp = w * 64 + mfi * 16 + lr;
      int gb = colp * 256 + kk * 64 + (lg << 4);
      ah[mfi] = *(const bf16x8*)(o1h + gb);
      al[mfi] = *(const bf16x8*)(o1l + gb);
    }
#pragma unroll
    for (int nfi = 0; nfi < 2; ++nfi) {
      int row = nfi * 16 + lr;
      int off = (row * 256 + kk * 64 + (lg << 4)) ^ ((row & 7) << 4);
      bh[nfi] = *(const bf16x8*)(augHi + off);
      bl[nfi] = *(const bf16x8*)(augLo + off);
    }
#pragma unroll
    for (int mfi = 0; mfi < 4; ++mfi)
#pragma unroll
      for (int nfi = 0; nfi < 2; ++nfi) {
        acc[mfi][nfi] = MFMA16(ah[mfi], bh[nfi], acc[mfi][nfi]);
        acc[mfi][nfi] = MFMA16(ah[mfi], bl[nfi], acc[mfi][nfi]);
        acc[mfi][nfi] = MFMA16(al[mfi], bh[nfi], acc[mfi][nfi]);
      }
  }
#pragma unroll
  for (int mfi = 0; mfi < 4; ++mfi) {
    int col0 = w * 64 + mfi * 16 + (lg << 2);
    f32x4 bv = *(const f32x4*)(bo1 + col0);
#pragma unroll
    for (int nfi = 0; nfi < 2; ++nfi) {
      int row = nfi * 16 + lr;
      U64q ph, pl;
#pragma unroll
      for (int i2 = 0; i2 < 4; ++i2) {
        float x = fmaxf(acc[mfi][nfi][i2] + bv[i2], 0.f);
        ph.q[i2] = (__bf16)x;
        pl.q[i2] = (__bf16)(x - (float)ph.q[i2]);
      }
      int off = (row * 512 + col0 * 2) ^ ((row & 7) << 4);
      *(unsigned long long*)(h1hi + off) = ph.u;
      *(unsigned long long*)(h1lo + off) = pl.u;
    }
  }
  __syncthreads();

  f32x4 acc2[4][2] = {};
#pragma unroll
  for (int kk = 0; kk < 8; ++kk) {
    bf16x8 ah[4], al[4], bh[2], bl[2];
#pragma unroll
    for (int mfi = 0; mfi < 4; ++mfi) {
      int colp = w * 64 + mfi * 16 + lr;
      int gb = colp * 512 + kk * 64 + (lg << 4);
      ah[mfi] = *(const bf16x8*)(o2h + gb);
      al[mfi] = *(const bf16x8*)(o2l + gb);
    }
#pragma unroll
    for (int nfi = 0; nfi < 2; ++nfi) {
      int row = nfi * 16 + lr;
      int off = (row * 512 + kk * 64 + (lg << 4)) ^ ((row & 7) << 4);
      bh[nfi] = *(const bf16x8*)(h1hi + off);
      bl[nfi] = *(const bf16x8*)(h1lo + off);
    }
#pragma unroll
    for (int mfi = 0; mfi < 4; ++mfi)
#pragma unroll
      for (int nfi = 0; nfi < 2; ++nfi) {
        acc2[mfi][nfi] = MFMA16(ah[mfi], bh[nfi], acc2[mfi][nfi]);
        acc2[mfi][nfi] = MFMA16(ah[mfi], bl[nfi], acc2[mfi][nfi]);
        acc2[mfi][nfi] = MFMA16(al[mfi], bh[nfi], acc2[mfi][nfi]);
      }
  }
#pragma unroll
  for (int mfi = 0; mfi < 4; ++mfi) {
    int col0 = w * 64 + mfi * 16 + (lg << 2);
    f32x4 bv = *(const f32x4*)(bo2 + col0);
#pragma unroll
    for (int nfi = 0; nfi < 2; ++nfi) {
      int row = nfi * 16 + lr;
      U64q ph, pl;
#pragma unroll
      for (int i2 = 0; i2 < 4; ++i2) {
        float x = fmaxf(acc2[mfi][nfi][i2] + bv[i2], 0.f);
        ph.q[i2] = (__bf16)x;
        pl.q[i2] = (__bf16)(x - (float)ph.q[i2]);
      }
      int off = (row * 512 + col0 * 2) ^ ((row & 7) << 4);
      *(unsigned long long*)(h2hi + off) = ph.u;
      *(unsigned long long*)(h2lo + off) = pl.u;
    }
  }
  __syncthreads();

  f32x4 acc3[2] = {};
#pragma unroll
  for (int kk = 0; kk < 8; ++kk) {
    int colp = w * 16 + lr;
    int gb = colp * 512 + kk * 64 + (lg << 4);
    bf16x8 a3h = *(const bf16x8*)(o3h + gb);
    bf16x8 a3l = *(const bf16x8*)(o3l + gb);
#pragma unroll
    for (int nfi = 0; nfi < 2; ++nfi) {
      int row = nfi * 16 + lr;
      int off = (row * 512 + kk * 64 + (lg << 4)) ^ ((row & 7) << 4);
      bf16x8 b3h = *(const bf16x8*)(h2hi + off);
      bf16x8 b3l = *(const bf16x8*)(h2lo + off);
      acc3[nfi] = MFMA16(a3h, b3h, acc3[nfi]);
      acc3[nfi] = MFMA16(a3h, b3l, acc3[nfi]);
      acc3[nfi] = MFMA16(a3l, b3h, acc3[nfi]);
    }
  }
#pragma unroll
  for (int nfi = 0; nfi < 2; ++nfi) {
    int row = nfi * 16 + lr;
    int col0 = w * 16 + (lg << 2);
    f32x4 bv = *(const f32x4*)(bo3 + col0);
    f32x4 iv = *(const f32x4*)(inputs + (r0 + row) * 64 + col0);
    f32x4 o;
#pragma unroll
    for (int i2 = 0; i2 < 4; ++i2) o[i2] = acc3[nfi][i2] + bv[i2] + iv[i2];
    *(f32x4*)(out + (r0 + row) * 64 + col0) = o;
  }
}

// ===========================================================================
extern "C" void kernel_launch(void* const* d_in, const int* in_sizes, int n_in,
                              void* d_out, int out_size, void* d_ws, size_t ws_size,
                              hipStream_t stream) {
  (void)in_sizes; (void)n_in; (void)out_size;
  if (ws_size < (size_t)WS_NEED) return;  // ~17.8 MB

  const float* inputs   = (const float*)d_in[0];
  const float* rel_type = (const float*)d_in[1];
  const float* W1  = (const float*)d_in[4];
  const float* b1  = (const float*)d_in[5];
  const float* W2  = (const float*)d_in[6];
  const float* b2  = (const float*)d_in[7];
  const float* Wo1 = (const float*)d_in[8];
  const float* bo1 = (const float*)d_in[9];
  const float* Wo2 = (const float*)d_in[10];
  const float* bo2 = (const float*)d_in[11];
  const float* Wo3 = (const float*)d_in[12];
  const float* bo3 = (const float*)d_in[13];

  char* ws = (char*)d_ws;
  float* agg = (float*)(ws + WS_AGG);
  float* out = (float*)d_out;

  k0_convert<<<dim3(2240), dim3(256), 0, stream>>>(W1, W2, Wo1, Wo2, Wo3, ws);
  kPQ<<<dim3(128), dim3(256), 0, stream>>>(inputs, b1, ws, ws);
  k1_edge<<<dim3(1024), dim3(256), 0, stream>>>(rel_type, b2, ws, agg);
  k3_node<<<dim3(128), dim3(256), 0, stream>>>(inputs, agg, ws, bo1, bo2, bo3, out);
}